// Round 1
// 1107.853 us; speedup vs baseline: 1.6809x; 1.6809x over previous
//
#include <hip/hip_runtime.h>

#define BH  24
#define SEQ 4096
#define DIM 128
#define FF  256
#define CHK 128
#define NC  32
#define SLOT (FF*DIM)

typedef unsigned short u16;
typedef unsigned int   u32;
typedef short  s16x8 __attribute__((ext_vector_type(8)));
typedef float  f32x4 __attribute__((ext_vector_type(4)));

#define MFMA16(a,b,c) __builtin_amdgcn_mfma_f32_16x16x32_bf16(a,b,c,0,0,0)

static __device__ __forceinline__ float bf2f(u16 u) {
    return __uint_as_float(((u32)u) << 16);
}
static __device__ __forceinline__ u16 f2bf(float f) {
    u32 u = __float_as_uint(f);
    u += 0x7fffu + ((u >> 16) & 1u);
    return (u16)(u >> 16);
}

// ---------------- weight prep: transposed, padded, bf16 ----------------------
// w1t[f][d]  stride 136  (B-operand for GEMM1: col=f, k=d)
// w2t[e][f]  stride 264  (B-operand for GEMM2: col=e, k=f)
__global__ __launch_bounds__(256) void prep_kernel(
    const float* __restrict__ w1, const float* __restrict__ w2,
    u16* __restrict__ w1t, u16* __restrict__ w2t)
{
    int idx = blockIdx.x * 256 + threadIdx.x;
    int stride = gridDim.x * 256;
    for (int i = idx; i < 256*136; i += stride) {
        int f = i / 136, d = i - f*136;
        w1t[i] = (d < 128) ? f2bf(w1[d*FF + f]) : (u16)0;
    }
    for (int i = idx; i < 256*264; i += stride) {
        int e = i / 264, f = i - e*264;
        w2t[i] = (f < 256) ? f2bf(w2[f*FF + e]) : (u16)0;
    }
}

// ---------------- fused phi via MFMA: y = silu(x@W1+b1)@W2 + b2 --------------
// 512 threads (8 waves, 2x4 wave grid), 128 tokens/block.
// LDS arena (u16 units), all strides odd multiples of 8 u16 (16B granules):
//   phase A: XS [128][136] @0, W1S [256][136] @17408        -> 52224 u16
//   phase B: HS [128][264] @0, W2S chunk [256][72] @33792   -> 52224 u16
//   epilog : YB [128][264] @0
#define PTOK 128
#define XS_OFF   0
#define W1S_OFF  17408
#define HS_OFF   0
#define W2S_OFF  33792
#define YB_OFF   0
#define ARENA_U16 52224   // 104,448 B

__global__ __launch_bounds__(512) void phi_fused_kernel(
    const float* __restrict__ xq, const float* __restrict__ xk,
    const float* __restrict__ b1, const float* __restrict__ b2,
    const u16* __restrict__ w1t, const u16* __restrict__ w2t,
    u16* __restrict__ yq, u16* __restrict__ yk)
{
    __shared__ __align__(16) u16 arena[ARENA_U16];
    const int tid = threadIdx.x;
    int b = blockIdx.x;
    const int nB = (BH*SEQ)/PTOK;   // 768
    const float* xin; u16* yout;
    if (b < nB) { xin = xq; yout = yq; }
    else        { xin = xk; yout = yk; b -= nB; }
    const size_t tok0 = (size_t)b * PTOK;

    const int w = tid >> 6, lane = tid & 63;
    const int m = lane & 15, q = lane >> 4;
    const int wr = w >> 2, wc = w & 3;        // 2 row-groups x 4 col-groups
    const f32x4 zero4 = {0.f, 0.f, 0.f, 0.f};

    // ---- stage XS (fp32 -> bf16) + W1S (linear copy of pre-padded w1t) -----
    {
        const float4* xsrc = reinterpret_cast<const float4*>(xin + tok0*DIM);
        for (int i = tid; i < PTOK*DIM/4; i += 512) {
            int row = i >> 5, c4 = i & 31;
            float4 xv = xsrc[i];
            u32 lo = (u32)f2bf(xv.x) | ((u32)f2bf(xv.y) << 16);
            u32 hi = (u32)f2bf(xv.z) | ((u32)f2bf(xv.w) << 16);
            *reinterpret_cast<uint2*>(arena + XS_OFF + row*136 + c4*4) = make_uint2(lo, hi);
        }
        const uint4* s = reinterpret_cast<const uint4*>(w1t);
        uint4* d = reinterpret_cast<uint4*>(arena + W1S_OFF);
        for (int i = tid; i < (256*136)/8; i += 512) d[i] = s[i];
    }
    __syncthreads();

    // ---- GEMM1: H[128][256] = XS @ W1, K=128 -------------------------------
    f32x4 acc[4][4];
    #pragma unroll
    for (int i = 0; i < 4; ++i)
        #pragma unroll
        for (int ct = 0; ct < 4; ++ct) acc[i][ct] = zero4;

    for (int kk = 0; kk < 4; ++kk) {
        int ko = kk*32 + q*8;
        s16x8 a[4], bb[4];
        #pragma unroll
        for (int i = 0; i < 4; ++i)
            a[i] = *reinterpret_cast<const s16x8*>(arena + XS_OFF + (wr*64 + i*16 + m)*136 + ko);
        #pragma unroll
        for (int ct = 0; ct < 4; ++ct)
            bb[ct] = *reinterpret_cast<const s16x8*>(arena + W1S_OFF + (wc*64 + ct*16 + m)*136 + ko);
        #pragma unroll
        for (int i = 0; i < 4; ++i)
            #pragma unroll
            for (int ct = 0; ct < 4; ++ct)
                acc[i][ct] = MFMA16(a[i], bb[ct], acc[i][ct]);
    }
    __syncthreads();   // all XS/W1S reads done; HS overwrites that space

    // ---- bias + SiLU, write HS bf16 ----------------------------------------
    {
        float b1v[4];
        #pragma unroll
        for (int ct = 0; ct < 4; ++ct) b1v[ct] = b1[wc*64 + ct*16 + m];
        #pragma unroll
        for (int i = 0; i < 4; ++i) {
            #pragma unroll
            for (int ct = 0; ct < 4; ++ct) {
                #pragma unroll
                for (int reg = 0; reg < 4; ++reg) {
                    float h = acc[i][ct][reg] + b1v[ct];
                    h = h / (1.0f + __expf(-h));
                    arena[HS_OFF + (size_t)(wr*64 + i*16 + q*4 + reg)*264 + (wc*64 + ct*16 + m)] = f2bf(h);
                }
            }
        }
    }
    __syncthreads();

    // ---- GEMM2: Y[128][256] = HS @ W2, K=256 in 4 chunks of 64 -------------
    f32x4 acc2[4][4];
    #pragma unroll
    for (int i = 0; i < 4; ++i)
        #pragma unroll
        for (int ct = 0; ct < 4; ++ct) acc2[i][ct] = zero4;

    for (int ch = 0; ch < 4; ++ch) {
        {   // stage W2 chunk [256 e][64 f] -> [256][72] (prev reads fenced below)
            const uint4* s = reinterpret_cast<const uint4*>(w2t);
            uint4* d = reinterpret_cast<uint4*>(arena + W2S_OFF);
            for (int i = tid; i < 256*8; i += 512) {
                int e = i >> 3, c = i & 7;
                d[e*9 + c] = s[e*33 + ch*8 + c];
            }
        }
        __syncthreads();
        #pragma unroll
        for (int k2 = 0; k2 < 2; ++k2) {
            int ko = k2*32 + q*8;
            s16x8 a[4], bb[4];
            #pragma unroll
            for (int i = 0; i < 4; ++i)
                a[i] = *reinterpret_cast<const s16x8*>(arena + HS_OFF + (wr*64 + i*16 + m)*264 + ch*64 + ko);
            #pragma unroll
            for (int ct = 0; ct < 4; ++ct)
                bb[ct] = *reinterpret_cast<const s16x8*>(arena + W2S_OFF + (wc*64 + ct*16 + m)*72 + ko);
            #pragma unroll
            for (int i = 0; i < 4; ++i)
                #pragma unroll
                for (int ct = 0; ct < 4; ++ct)
                    acc2[i][ct] = MFMA16(a[i], bb[ct], acc2[i][ct]);
        }
        __syncthreads();   // chunk reads done; next stage may overwrite W2S
    }

    // ---- bias, Y -> LDS (whole arena dead), coalesced uint4 store ----------
    {
        float b2v[4];
        #pragma unroll
        for (int ct = 0; ct < 4; ++ct) b2v[ct] = b2[wc*64 + ct*16 + m];
        #pragma unroll
        for (int i = 0; i < 4; ++i) {
            #pragma unroll
            for (int ct = 0; ct < 4; ++ct) {
                #pragma unroll
                for (int reg = 0; reg < 4; ++reg) {
                    float y = acc2[i][ct][reg] + b2v[ct];
                    arena[YB_OFF + (size_t)(wr*64 + i*16 + q*4 + reg)*264 + (wc*64 + ct*16 + m)] = f2bf(y);
                }
            }
        }
    }
    __syncthreads();
    {
        uint4* dst = reinterpret_cast<uint4*>(yout + tok0*FF);
        const uint4* srcy = reinterpret_cast<const uint4*>(arena + YB_OFF);
        for (int i = tid; i < PTOK*32; i += 512) {
            int row = i >> 5, c = i & 31;
            dst[i] = srcy[row*33 + c];
        }
    }
}

// ------- per-(head,chunk) KV sums -> bf16 TRANSPOSED [d][f] (R3 producer) ----
// chunkT[h][c][d][f] = sum_t kphi[t][f] * v[t][d]
__global__ __launch_bounds__(256) void kvsum_kernel(
    const u16* __restrict__ kphi, const float* __restrict__ v,
    u16* __restrict__ chunkT)
{
    __shared__ u16 ks[CHK*FF];   // 64 KB bf16 kphi chunk
    const int c = blockIdx.x, h = blockIdx.y, tid = threadIdx.x;
    const size_t tok0 = (size_t)h*SEQ + (size_t)c*CHK;
    {
        const uint4* src = reinterpret_cast<const uint4*>(kphi + tok0*FF);
        uint4* dst = reinterpret_cast<uint4*>(ks);
        for (int i = tid; i < CHK*FF/8; i += 256) dst[i] = src[i];
    }
    __syncthreads();
    const int d  = tid & 127;
    const int fh = (tid >> 7) * 128;
    float acc[128];
    #pragma unroll
    for (int i = 0; i < 128; ++i) acc[i] = 0.f;
    for (int t = 0; t < CHK; ++t) {
        float vval = v[(tok0 + t)*DIM + d];
        const uint2* kr = reinterpret_cast<const uint2*>(ks + t*FF + fh);
        #pragma unroll
        for (int f4 = 0; f4 < 32; ++f4) {
            uint2 kk = kr[f4];
            acc[f4*4+0] += vval * __uint_as_float(kk.x << 16);
            acc[f4*4+1] += vval * __uint_as_float(kk.x & 0xffff0000u);
            acc[f4*4+2] += vval * __uint_as_float(kk.y << 16);
            acc[f4*4+3] += vval * __uint_as_float(kk.y & 0xffff0000u);
        }
    }
    u16* outp = chunkT + ((size_t)(h*NC + c))*SLOT + (size_t)d*FF + fh;
    #pragma unroll
    for (int f4 = 0; f4 < 32; ++f4) {
        u32 lo = (u32)f2bf(acc[f4*4+0]) | ((u32)f2bf(acc[f4*4+1]) << 16);
        u32 hi = (u32)f2bf(acc[f4*4+2]) | ((u32)f2bf(acc[f4*4+3]) << 16);
        *reinterpret_cast<uint2*>(outp + f4*4) = make_uint2(lo, hi);
    }
}

// ---------------- elementwise scan over chunks (layout-agnostic, proven) -----
__global__ __launch_bounds__(256) void scan_kernel(
    u16* __restrict__ chunkT, u16* __restrict__ sufT)
{
    const int g = blockIdx.x * 256 + threadIdx.x;
    const int h = g >> 12;
    const int e = (g & 4095) * 8;
    u16* base  = chunkT + (size_t)h*NC*SLOT + e;
    u16* sbase = sufT   + (size_t)h*NC*SLOT + e;

    float tot[8];
    #pragma unroll
    for (int i = 0; i < 8; ++i) tot[i] = 0.f;
    for (int c = 0; c < NC; ++c) {
        uint4 r = *reinterpret_cast<const uint4*>(base + (size_t)c*SLOT);
        tot[0] += __uint_as_float(r.x << 16);
        tot[1] += __uint_as_float(r.x & 0xffff0000u);
        tot[2] += __uint_as_float(r.y << 16);
        tot[3] += __uint_as_float(r.y & 0xffff0000u);
        tot[4] += __uint_as_float(r.z << 16);
        tot[5] += __uint_as_float(r.z & 0xffff0000u);
        tot[6] += __uint_as_float(r.w << 16);
        tot[7] += __uint_as_float(r.w & 0xffff0000u);
    }
    float run[8];
    #pragma unroll
    for (int i = 0; i < 8; ++i) run[i] = 0.f;
    for (int c = 0; c < NC; ++c) {
        uint4 r = *reinterpret_cast<const uint4*>(base + (size_t)c*SLOT);
        float old[8];
        old[0] = __uint_as_float(r.x << 16);
        old[1] = __uint_as_float(r.x & 0xffff0000u);
        old[2] = __uint_as_float(r.y << 16);
        old[3] = __uint_as_float(r.y & 0xffff0000u);
        old[4] = __uint_as_float(r.z << 16);
        old[5] = __uint_as_float(r.z & 0xffff0000u);
        old[6] = __uint_as_float(r.w << 16);
        old[7] = __uint_as_float(r.w & 0xffff0000u);
        uint4 wp, wsuf;
        wp.x = (u32)f2bf(run[0]) | ((u32)f2bf(run[1]) << 16);
        wp.y = (u32)f2bf(run[2]) | ((u32)f2bf(run[3]) << 16);
        wp.z = (u32)f2bf(run[4]) | ((u32)f2bf(run[5]) << 16);
        wp.w = (u32)f2bf(run[6]) | ((u32)f2bf(run[7]) << 16);
        *reinterpret_cast<uint4*>(base + (size_t)c*SLOT) = wp;
        #pragma unroll
        for (int i = 0; i < 8; ++i) run[i] += old[i];
        float sf[8];
        #pragma unroll
        for (int i = 0; i < 8; ++i) sf[i] = tot[i] - run[i];
        wsuf.x = (u32)f2bf(sf[0]) | ((u32)f2bf(sf[1]) << 16);
        wsuf.y = (u32)f2bf(sf[2]) | ((u32)f2bf(sf[3]) << 16);
        wsuf.z = (u32)f2bf(sf[4]) | ((u32)f2bf(sf[5]) << 16);
        wsuf.w = (u32)f2bf(sf[6]) | ((u32)f2bf(sf[7]) << 16);
        *reinterpret_cast<uint4*>(sbase + (size_t)c*SLOT) = wsuf;
    }
}

// ------- output: MFMA scores (proven) + scalar intra (proven) + MFMA inter ---
__global__ __launch_bounds__(256) void out_kernel(
    const u16* __restrict__ qphi, const u16* __restrict__ kphi,
    const float* __restrict__ v,
    const u16* __restrict__ prefT, const u16* __restrict__ sufT,
    float* __restrict__ out)
{
    __shared__ float sT[CHK*CHK];    // 64 KB: scores sT[j][i], then inter buffer
    const int c = blockIdx.x, h = blockIdx.y;
    const int tid = threadIdx.x;
    const int w = tid >> 6, lane = tid & 63;
    const int m = lane & 15, q = lane >> 4;
    const size_t tok0 = (size_t)h*SEQ + (size_t)c*CHK;
    const u16* qbase = qphi + tok0*FF;
    const u16* kbase = kphi + tok0*FF;
    const int rowA0 = (2*w)*16 + m, rowA1 = (2*w+1)*16 + m;
    f32x4 zero4 = {0.f, 0.f, 0.f, 0.f};

    // ---- phase 1: S = Qphi Kphi^T via MFMA, fp32 -> sT[j*CHK + i]  [R4] ----
    {
        f32x4 sacc[2][8];
        #pragma unroll
        for (int r = 0; r < 2; ++r)
            #pragma unroll
            for (int ct = 0; ct < 8; ++ct) sacc[r][ct] = zero4;

        for (int kk = 0; kk < 8; ++kk) {
            int ko = kk*32 + q*8;
            s16x8 a0 = *reinterpret_cast<const s16x8*>(qbase + (size_t)rowA0*FF + ko);
            s16x8 a1 = *reinterpret_cast<const s16x8*>(qbase + (size_t)rowA1*FF + ko);
            #pragma unroll
            for (int ct = 0; ct < 8; ++ct) {
                s16x8 b = *reinterpret_cast<const s16x8*>(kbase + (size_t)(ct*16 + m)*FF + ko);
                sacc[0][ct] = MFMA16(a0, b, sacc[0][ct]);
                sacc[1][ct] = MFMA16(a1, b, sacc[1][ct]);
            }
        }
        // C/D layout (HW-pinned in R4): col = lane&15, row = q*4 + reg
        #pragma unroll
        for (int r = 0; r < 2; ++r) {
            #pragma unroll
            for (int ct = 0; ct < 8; ++ct) {
                int col = ct*16 + m;
                #pragma unroll
                for (int reg = 0; reg < 4; ++reg) {
                    int row = (2*w + r)*16 + q*4 + reg;
                    sT[col*CHK + row] = sacc[r][ct][reg];
                }
            }
        }
    }
    __syncthreads();

    // ---- phase 2: scalar intra-chunk (R4-proven), both dc, accs in regs ----
    const int i    = tid >> 1;
    const int half = tid & 1;
    const float* vbase = v + tok0*DIM;
    float accA[2][32], accB[2][32];
    #pragma unroll
    for (int dc = 0; dc < 2; ++dc)
        #pragma unroll
        for (int t = 0; t < 32; ++t) { accA[dc][t] = 0.f; accB[dc][t] = 0.f; }

    for (int j = 0; j < CHK; ++j) {
        float s = sT[(size_t)j*CHK + i];
        bool fa = (j <= i), fb = (j >= i);
        #pragma unroll
        for (int dc = 0; dc < 2; ++dc) {
            const int dbase = half*64 + dc*32;
            const float4* vr = reinterpret_cast<const float4*>(vbase + (size_t)j*DIM + dbase);
            float4 vv[8];
            #pragma unroll
            for (int d4 = 0; d4 < 8; ++d4) vv[d4] = vr[d4];
            if (fa) {
                #pragma unroll
                for (int d4 = 0; d4 < 8; ++d4) {
                    accA[dc][d4*4+0] += s*vv[d4].x; accA[dc][d4*4+1] += s*vv[d4].y;
                    accA[dc][d4*4+2] += s*vv[d4].z; accA[dc][d4*4+3] += s*vv[d4].w;
                }
            }
            if (fb) {
                #pragma unroll
                for (int d4 = 0; d4 < 8; ++d4) {
                    accB[dc][d4*4+0] += s*vv[d4].x; accB[dc][d4*4+1] += s*vv[d4].y;
                    accB[dc][d4*4+2] += s*vv[d4].z; accB[dc][d4*4+3] += s*vv[d4].w;
                }
            }
        }
    }
    __syncthreads();   // sT (scores) dead

    // ---- phase 3: inter-chunk via MFMA; redistribute via rotated LDS --------
    // D[row=i][col=d] = sum_f Q[i][f] * state[f][d]; B from [d][f] layout.
    const u16* pf = prefT + (size_t)(h*NC + c)*SLOT;
    const u16* sf = sufT  + (size_t)(h*NC + c)*SLOT;
    #pragma unroll
    for (int stream = 0; stream < 2; ++stream) {
        const u16* st = (stream == 0) ? pf : sf;
        f32x4 cd[2][8];
        #pragma unroll
        for (int r = 0; r < 2; ++r)
            #pragma unroll
            for (int nt = 0; nt < 8; ++nt) cd[r][nt] = zero4;

        for (int kk = 0; kk < 8; ++kk) {
            int ko = kk*32 + q*8;
            s16x8 a0 = *reinterpret_cast<const s16x8*>(qbase + (size_t)rowA0*FF + ko);
            s16x8 a1 = *reinterpret_cast<const s16x8*>(qbase + (size_t)rowA1*FF + ko);
            #pragma unroll
            for (int nt = 0; nt < 8; ++nt) {
                s16x8 b = *reinterpret_cast<const s16x8*>(st + (size_t)(nt*16 + m)*FF + ko);
                cd[0][nt] = MFMA16(a0, b, cd[0][nt]);
                cd[1][nt] = MFMA16(a1, b, cd[1][nt]);
            }
        }
        // write D to LDS with +row rotation (conflict-free absorb reads)
        #pragma unroll
        for (int r = 0; r < 2; ++r) {
            #pragma unroll
            for (int nt = 0; nt < 8; ++nt) {
                int col = nt*16 + m;
                #pragma unroll
                for (int reg = 0; reg < 4; ++reg) {
                    int row = (2*w + r)*16 + q*4 + reg;
                    sT[row*CHK + ((col + row) & 127)] = cd[r][nt][reg];
                }
            }
        }
        __syncthreads();
        // absorb into scalar accs
        #pragma unroll
        for (int dc = 0; dc < 2; ++dc) {
            const int dbase = half*64 + dc*32;
            if (stream == 0) {
                #pragma unroll
                for (int t = 0; t < 32; ++t)
                    accA[dc][t] += sT[i*CHK + ((dbase + t + i) & 127)];
            } else {
                #pragma unroll
                for (int t = 0; t < 32; ++t)
                    accB[dc][t] += sT[i*CHK + ((dbase + t + i) & 127)];
            }
        }
        __syncthreads();
    }

    // ---- epilogue (R4-proven mapping) ----
    const int pos = c*CHK + i;
    const float ia = 1.0f / (float)(pos + 1);
    const float ib = 1.0f / (float)(SEQ - pos);
    float* orow = out + (tok0 + (size_t)i)*DIM;
    #pragma unroll
    for (int dc = 0; dc < 2; ++dc) {
        const int dbase = half*64 + dc*32;
        #pragma unroll
        for (int d4 = 0; d4 < 8; ++d4) {
            float4 o;
            o.x = accA[dc][d4*4+0]*ia + accB[dc][d4*4+0]*ib;
            o.y = accA[dc][d4*4+1]*ia + accB[dc][d4*4+1]*ib;
            o.z = accA[dc][d4*4+2]*ia + accB[dc][d4*4+2]*ib;
            o.w = accA[dc][d4*4+3]*ia + accB[dc][d4*4+3]*ib;
            *reinterpret_cast<float4*>(&orow[dbase + d4*4]) = o;
        }
    }
}

extern "C" void kernel_launch(void* const* d_in, const int* in_sizes, int n_in,
                              void* d_out, int out_size, void* d_ws, size_t ws_size,
                              hipStream_t stream) {
    const float* q  = (const float*)d_in[0];
    const float* k  = (const float*)d_in[1];
    const float* v  = (const float*)d_in[2];
    const float* w1 = (const float*)d_in[3];
    const float* b1 = (const float*)d_in[4];
    const float* w2 = (const float*)d_in[5];
    const float* b2 = (const float*)d_in[6];
    float* out = (float*)d_out;

    char* ws = (char*)d_ws;
    const size_t phiBytes = (size_t)BH*SEQ*FF*sizeof(u16);   // 50,331,648
    u16* qphi   = (u16*)ws;
    u16* kphi   = (u16*)(ws + phiBytes);
    u16* chunkT = (u16*)(ws + 2*phiBytes);   // becomes prefT in-place after scan
    u16* sufT   = (u16*)(ws + 3*phiBytes);
    u16* w1t    = (u16*)(ws + 4*phiBytes);               // 256*136*2 = 69,632 B
    u16* w2t    = w1t + 256*136;                         // 256*264*2 = 135,168 B
    // total ws = 201,326,592 + 204,800 = 201,531,392 B (< 204,472,320 proven)

    prep_kernel<<<dim3(100), 256, 0, stream>>>(w1, w2, w1t, w2t);
    phi_fused_kernel<<<dim3(2*(BH*SEQ)/PTOK), 512, 0, stream>>>(q, k, b1, b2, w1t, w2t, qphi, kphi);
    kvsum_kernel<<<dim3(NC, BH), 256, 0, stream>>>(kphi, v, chunkT);
    scan_kernel<<<dim3(384), 256, 0, stream>>>(chunkT, sufT);
    out_kernel<<<dim3(NC, BH), 256, 0, stream>>>(qphi, kphi, v, chunkT, sufT, out);
}

// Round 2
// 732.307 us; speedup vs baseline: 2.5429x; 1.5128x over previous
//
#include <hip/hip_runtime.h>

#define BH  24
#define SEQ 4096
#define DIM 128
#define FF  256
#define CHK 128
#define NC  32
#define SLOT (FF*DIM)

typedef unsigned short u16;
typedef unsigned int   u32;
typedef short  s16x8 __attribute__((ext_vector_type(8)));
typedef float  f32x4 __attribute__((ext_vector_type(4)));

#define MFMA16(a,b,c) __builtin_amdgcn_mfma_f32_16x16x32_bf16(a,b,c,0,0,0)

static __device__ __forceinline__ float bf2f(u16 u) {
    return __uint_as_float(((u32)u) << 16);
}
static __device__ __forceinline__ u16 f2bf(float f) {
    u32 u = __float_as_uint(f);
    u += 0x7fffu + ((u >> 16) & 1u);
    return (u16)(u >> 16);
}

// ---------------- weight prep: transposed, padded, bf16 ----------------------
// w1t[f][d]  stride 136  (B-operand for GEMM1: col=f, k=d)
// w2t[e][f]  stride 264  (B-operand for GEMM2: col=e, k=f)
__global__ __launch_bounds__(256) void prep_kernel(
    const float* __restrict__ w1, const float* __restrict__ w2,
    u16* __restrict__ w1t, u16* __restrict__ w2t)
{
    int idx = blockIdx.x * 256 + threadIdx.x;
    int stride = gridDim.x * 256;
    for (int i = idx; i < 256*136; i += stride) {
        int f = i / 136, d = i - f*136;
        w1t[i] = (d < 128) ? f2bf(w1[d*FF + f]) : (u16)0;
    }
    for (int i = idx; i < 256*264; i += stride) {
        int e = i / 264, f = i - e*264;
        w2t[i] = (f < 256) ? f2bf(w2[f*FF + e]) : (u16)0;
    }
}

// ---------------- fused phi via MFMA: y = silu(x@W1+b1)@W2 + b2 --------------
#define PTOK 128
#define XS_OFF   0
#define W1S_OFF  17408
#define HS_OFF   0
#define W2S_OFF  33792
#define YB_OFF   0
#define ARENA_U16 52224   // 104,448 B

__global__ __launch_bounds__(512) void phi_fused_kernel(
    const float* __restrict__ xq, const float* __restrict__ xk,
    const float* __restrict__ b1, const float* __restrict__ b2,
    const u16* __restrict__ w1t, const u16* __restrict__ w2t,
    u16* __restrict__ yq, u16* __restrict__ yk)
{
    __shared__ __align__(16) u16 arena[ARENA_U16];
    const int tid = threadIdx.x;
    int b = blockIdx.x;
    const int nB = (BH*SEQ)/PTOK;   // 768
    const float* xin; u16* yout;
    if (b < nB) { xin = xq; yout = yq; }
    else        { xin = xk; yout = yk; b -= nB; }
    const size_t tok0 = (size_t)b * PTOK;

    const int w = tid >> 6, lane = tid & 63;
    const int m = lane & 15, q = lane >> 4;
    const int wr = w >> 2, wc = w & 3;        // 2 row-groups x 4 col-groups
    const f32x4 zero4 = {0.f, 0.f, 0.f, 0.f};

    // ---- stage XS (fp32 -> bf16) + W1S (linear copy of pre-padded w1t) -----
    {
        const float4* xsrc = reinterpret_cast<const float4*>(xin + tok0*DIM);
        for (int i = tid; i < PTOK*DIM/4; i += 512) {
            int row = i >> 5, c4 = i & 31;
            float4 xv = xsrc[i];
            u32 lo = (u32)f2bf(xv.x) | ((u32)f2bf(xv.y) << 16);
            u32 hi = (u32)f2bf(xv.z) | ((u32)f2bf(xv.w) << 16);
            *reinterpret_cast<uint2*>(arena + XS_OFF + row*136 + c4*4) = make_uint2(lo, hi);
        }
        const uint4* s = reinterpret_cast<const uint4*>(w1t);
        uint4* d = reinterpret_cast<uint4*>(arena + W1S_OFF);
        for (int i = tid; i < (256*136)/8; i += 512) d[i] = s[i];
    }
    __syncthreads();

    // ---- GEMM1: H[128][256] = XS @ W1, K=128 -------------------------------
    f32x4 acc[4][4];
    #pragma unroll
    for (int i = 0; i < 4; ++i)
        #pragma unroll
        for (int ct = 0; ct < 4; ++ct) acc[i][ct] = zero4;

    for (int kk = 0; kk < 4; ++kk) {
        int ko = kk*32 + q*8;
        s16x8 a[4], bb[4];
        #pragma unroll
        for (int i = 0; i < 4; ++i)
            a[i] = *reinterpret_cast<const s16x8*>(arena + XS_OFF + (wr*64 + i*16 + m)*136 + ko);
        #pragma unroll
        for (int ct = 0; ct < 4; ++ct)
            bb[ct] = *reinterpret_cast<const s16x8*>(arena + W1S_OFF + (wc*64 + ct*16 + m)*136 + ko);
        #pragma unroll
        for (int i = 0; i < 4; ++i)
            #pragma unroll
            for (int ct = 0; ct < 4; ++ct)
                acc[i][ct] = MFMA16(a[i], bb[ct], acc[i][ct]);
    }
    __syncthreads();   // all XS/W1S reads done; HS overwrites that space

    // ---- bias + SiLU, write HS bf16 ----------------------------------------
    {
        float b1v[4];
        #pragma unroll
        for (int ct = 0; ct < 4; ++ct) b1v[ct] = b1[wc*64 + ct*16 + m];
        #pragma unroll
        for (int i = 0; i < 4; ++i) {
            #pragma unroll
            for (int ct = 0; ct < 4; ++ct) {
                #pragma unroll
                for (int reg = 0; reg < 4; ++reg) {
                    float h = acc[i][ct][reg] + b1v[ct];
                    h = h / (1.0f + __expf(-h));
                    arena[HS_OFF + (size_t)(wr*64 + i*16 + q*4 + reg)*264 + (wc*64 + ct*16 + m)] = f2bf(h);
                }
            }
        }
    }
    __syncthreads();

    // ---- GEMM2: Y[128][256] = HS @ W2, K=256 in 4 chunks of 64 -------------
    f32x4 acc2[4][4];
    #pragma unroll
    for (int i = 0; i < 4; ++i)
        #pragma unroll
        for (int ct = 0; ct < 4; ++ct) acc2[i][ct] = zero4;

    for (int ch = 0; ch < 4; ++ch) {
        {   // stage W2 chunk [256 e][64 f] -> [256][72]
            const uint4* s = reinterpret_cast<const uint4*>(w2t);
            uint4* d = reinterpret_cast<uint4*>(arena + W2S_OFF);
            for (int i = tid; i < 256*8; i += 512) {
                int e = i >> 3, c = i & 7;
                d[e*9 + c] = s[e*33 + ch*8 + c];
            }
        }
        __syncthreads();
        #pragma unroll
        for (int k2 = 0; k2 < 2; ++k2) {
            int ko = k2*32 + q*8;
            s16x8 a[4], bb[4];
            #pragma unroll
            for (int i = 0; i < 4; ++i)
                a[i] = *reinterpret_cast<const s16x8*>(arena + HS_OFF + (wr*64 + i*16 + m)*264 + ch*64 + ko);
            #pragma unroll
            for (int ct = 0; ct < 4; ++ct)
                bb[ct] = *reinterpret_cast<const s16x8*>(arena + W2S_OFF + (wc*64 + ct*16 + m)*72 + ko);
            #pragma unroll
            for (int i = 0; i < 4; ++i)
                #pragma unroll
                for (int ct = 0; ct < 4; ++ct)
                    acc2[i][ct] = MFMA16(a[i], bb[ct], acc2[i][ct]);
        }
        __syncthreads();
    }

    // ---- bias, Y -> LDS (whole arena dead), coalesced uint4 store ----------
    {
        float b2v[4];
        #pragma unroll
        for (int ct = 0; ct < 4; ++ct) b2v[ct] = b2[wc*64 + ct*16 + m];
        #pragma unroll
        for (int i = 0; i < 4; ++i) {
            #pragma unroll
            for (int ct = 0; ct < 4; ++ct) {
                #pragma unroll
                for (int reg = 0; reg < 4; ++reg) {
                    float y = acc2[i][ct][reg] + b2v[ct];
                    arena[YB_OFF + (size_t)(wr*64 + i*16 + q*4 + reg)*264 + (wc*64 + ct*16 + m)] = f2bf(y);
                }
            }
        }
    }
    __syncthreads();
    {
        uint4* dst = reinterpret_cast<uint4*>(yout + tok0*FF);
        const uint4* srcy = reinterpret_cast<const uint4*>(arena + YB_OFF);
        for (int i = tid; i < PTOK*32; i += 512) {
            int row = i >> 5, c = i & 31;
            dst[i] = srcy[row*33 + c];
        }
    }
}

// ------- per-(head,chunk) KV sums -> bf16 TRANSPOSED [d][f] (R3 producer) ----
__global__ __launch_bounds__(256) void kvsum_kernel(
    const u16* __restrict__ kphi, const float* __restrict__ v,
    u16* __restrict__ chunkT)
{
    __shared__ u16 ks[CHK*FF];   // 64 KB bf16 kphi chunk
    const int c = blockIdx.x, h = blockIdx.y, tid = threadIdx.x;
    const size_t tok0 = (size_t)h*SEQ + (size_t)c*CHK;
    {
        const uint4* src = reinterpret_cast<const uint4*>(kphi + tok0*FF);
        uint4* dst = reinterpret_cast<uint4*>(ks);
        for (int i = tid; i < CHK*FF/8; i += 256) dst[i] = src[i];
    }
    __syncthreads();
    const int d  = tid & 127;
    const int fh = (tid >> 7) * 128;
    float acc[128];
    #pragma unroll
    for (int i = 0; i < 128; ++i) acc[i] = 0.f;
    for (int t = 0; t < CHK; ++t) {
        float vval = v[(tok0 + t)*DIM + d];
        const uint2* kr = reinterpret_cast<const uint2*>(ks + t*FF + fh);
        #pragma unroll
        for (int f4 = 0; f4 < 32; ++f4) {
            uint2 kk = kr[f4];
            acc[f4*4+0] += vval * __uint_as_float(kk.x << 16);
            acc[f4*4+1] += vval * __uint_as_float(kk.x & 0xffff0000u);
            acc[f4*4+2] += vval * __uint_as_float(kk.y << 16);
            acc[f4*4+3] += vval * __uint_as_float(kk.y & 0xffff0000u);
        }
    }
    u16* outp = chunkT + ((size_t)(h*NC + c))*SLOT + (size_t)d*FF + fh;
    #pragma unroll
    for (int f4 = 0; f4 < 32; ++f4) {
        u32 lo = (u32)f2bf(acc[f4*4+0]) | ((u32)f2bf(acc[f4*4+1]) << 16);
        u32 hi = (u32)f2bf(acc[f4*4+2]) | ((u32)f2bf(acc[f4*4+3]) << 16);
        *reinterpret_cast<uint2*>(outp + f4*4) = make_uint2(lo, hi);
    }
}

// ---------------- elementwise scan over chunks (layout-agnostic, proven) -----
__global__ __launch_bounds__(256) void scan_kernel(
    u16* __restrict__ chunkT, u16* __restrict__ sufT)
{
    const int g = blockIdx.x * 256 + threadIdx.x;
    const int h = g >> 12;
    const int e = (g & 4095) * 8;
    u16* base  = chunkT + (size_t)h*NC*SLOT + e;
    u16* sbase = sufT   + (size_t)h*NC*SLOT + e;

    float tot[8];
    #pragma unroll
    for (int i = 0; i < 8; ++i) tot[i] = 0.f;
    for (int c = 0; c < NC; ++c) {
        uint4 r = *reinterpret_cast<const uint4*>(base + (size_t)c*SLOT);
        tot[0] += __uint_as_float(r.x << 16);
        tot[1] += __uint_as_float(r.x & 0xffff0000u);
        tot[2] += __uint_as_float(r.y << 16);
        tot[3] += __uint_as_float(r.y & 0xffff0000u);
        tot[4] += __uint_as_float(r.z << 16);
        tot[5] += __uint_as_float(r.z & 0xffff0000u);
        tot[6] += __uint_as_float(r.w << 16);
        tot[7] += __uint_as_float(r.w & 0xffff0000u);
    }
    float run[8];
    #pragma unroll
    for (int i = 0; i < 8; ++i) run[i] = 0.f;
    for (int c = 0; c < NC; ++c) {
        uint4 r = *reinterpret_cast<const uint4*>(base + (size_t)c*SLOT);
        float old[8];
        old[0] = __uint_as_float(r.x << 16);
        old[1] = __uint_as_float(r.x & 0xffff0000u);
        old[2] = __uint_as_float(r.y << 16);
        old[3] = __uint_as_float(r.y & 0xffff0000u);
        old[4] = __uint_as_float(r.z << 16);
        old[5] = __uint_as_float(r.z & 0xffff0000u);
        old[6] = __uint_as_float(r.w << 16);
        old[7] = __uint_as_float(r.w & 0xffff0000u);
        uint4 wp, wsuf;
        wp.x = (u32)f2bf(run[0]) | ((u32)f2bf(run[1]) << 16);
        wp.y = (u32)f2bf(run[2]) | ((u32)f2bf(run[3]) << 16);
        wp.z = (u32)f2bf(run[4]) | ((u32)f2bf(run[5]) << 16);
        wp.w = (u32)f2bf(run[6]) | ((u32)f2bf(run[7]) << 16);
        *reinterpret_cast<uint4*>(base + (size_t)c*SLOT) = wp;
        #pragma unroll
        for (int i = 0; i < 8; ++i) run[i] += old[i];
        float sf[8];
        #pragma unroll
        for (int i = 0; i < 8; ++i) sf[i] = tot[i] - run[i];
        wsuf.x = (u32)f2bf(sf[0]) | ((u32)f2bf(sf[1]) << 16);
        wsuf.y = (u32)f2bf(sf[2]) | ((u32)f2bf(sf[3]) << 16);
        wsuf.z = (u32)f2bf(sf[4]) | ((u32)f2bf(sf[5]) << 16);
        wsuf.w = (u32)f2bf(sf[6]) | ((u32)f2bf(sf[7]) << 16);
        *reinterpret_cast<uint4*>(sbase + (size_t)c*SLOT) = wsuf;
    }
}

// ------- output: all-MFMA. S->bf16 LDS; masked intra GEMMs; inter GEMMs -----
// accA (fwd, j<=i) and accB (bwd, j>=i) live in C-fragment registers through
// phases 2+3; epilogue stores directly. One barrier total.
__global__ __launch_bounds__(256) void out_kernel(
    const u16* __restrict__ qphi, const u16* __restrict__ kphi,
    const float* __restrict__ v,
    const u16* __restrict__ prefT, const u16* __restrict__ sufT,
    float* __restrict__ out)
{
    __shared__ __align__(16) u16 SF[CHK*136];   // S bf16 [i][j], stride 136 (17x16B: conflict-free)
    __shared__ __align__(16) u16 VT[DIM*136];   // v^T bf16 [d][j], stride 136
    const int c = blockIdx.x, h = blockIdx.y;
    const int tid = threadIdx.x;
    const int w = tid >> 6, lane = tid & 63;
    const int m = lane & 15, q = lane >> 4;
    const size_t tok0 = (size_t)h*SEQ + (size_t)c*CHK;
    const u16* qbase = qphi + tok0*FF;
    const u16* kbase = kphi + tok0*FF;
    const int R0 = (2*w)*16, R1 = R0 + 16;
    const int rowA0 = R0 + m, rowA1 = R1 + m;
    const f32x4 zero4 = {0.f, 0.f, 0.f, 0.f};

    // ---- stage V^T: gather 8 rows per lane, b128 LDS writes (lanes vary d:
    //      granule stride 17 == 1 mod 8 -> conflict-free) ---------------------
    {
        const int d  = tid & 127;
        const int j0 = (tid >> 7) * 8;
        const float* vb = v + tok0*DIM + d;
        for (int jb = 0; jb < 8; ++jb) {
            const int jbase = jb*16 + j0;
            float vals[8];
            #pragma unroll
            for (int t = 0; t < 8; ++t) vals[t] = vb[(size_t)(jbase + t)*DIM];
            uint4 p;
            p.x = (u32)f2bf(vals[0]) | ((u32)f2bf(vals[1]) << 16);
            p.y = (u32)f2bf(vals[2]) | ((u32)f2bf(vals[3]) << 16);
            p.z = (u32)f2bf(vals[4]) | ((u32)f2bf(vals[5]) << 16);
            p.w = (u32)f2bf(vals[6]) | ((u32)f2bf(vals[7]) << 16);
            *reinterpret_cast<uint4*>(VT + d*136 + jbase) = p;
        }
    }

    // ---- phase 1: S = Qphi Kphi^T via MFMA, write bf16 SF (own rows only) --
    {
        f32x4 sacc[2][8];
        #pragma unroll
        for (int r = 0; r < 2; ++r)
            #pragma unroll
            for (int ct = 0; ct < 8; ++ct) sacc[r][ct] = zero4;

        for (int kk = 0; kk < 8; ++kk) {
            int ko = kk*32 + q*8;
            s16x8 a0 = *reinterpret_cast<const s16x8*>(qbase + (size_t)rowA0*FF + ko);
            s16x8 a1 = *reinterpret_cast<const s16x8*>(qbase + (size_t)rowA1*FF + ko);
            #pragma unroll
            for (int ct = 0; ct < 8; ++ct) {
                s16x8 b = *reinterpret_cast<const s16x8*>(kbase + (size_t)(ct*16 + m)*FF + ko);
                sacc[0][ct] = MFMA16(a0, b, sacc[0][ct]);
                sacc[1][ct] = MFMA16(a1, b, sacc[1][ct]);
            }
        }
        // C/D layout: col = ct*16 + (lane&15), row = R + q*4 + reg
        #pragma unroll
        for (int r = 0; r < 2; ++r) {
            const int R = (r == 0) ? R0 : R1;
            #pragma unroll
            for (int ct = 0; ct < 8; ++ct) {
                #pragma unroll
                for (int reg = 0; reg < 4; ++reg)
                    SF[(size_t)(R + q*4 + reg)*136 + (ct*16 + m)] = f2bf(sacc[r][ct][reg]);
            }
        }
    }
    __syncthreads();   // VT visible to all waves (SF rows are same-wave)

    // ---- phases 2+3 accumulators (C-fragment layout, shared tiling) --------
    f32x4 accA[2][8], accB[2][8];
    #pragma unroll
    for (int r = 0; r < 2; ++r)
        #pragma unroll
        for (int ct = 0; ct < 8; ++ct) { accA[r][ct] = zero4; accB[r][ct] = zero4; }

    // ---- phase 2: intra via triangular-masked MFMA GEMMs (S_lds x VT_lds) --
    #pragma unroll
    for (int kk = 0; kk < 4; ++kk) {
        const int ko = kk*32 + q*8;
        s16x8 b[8];
        #pragma unroll
        for (int ct = 0; ct < 8; ++ct)
            b[ct] = *reinterpret_cast<const s16x8*>(VT + (size_t)(ct*16 + m)*136 + ko);
        #pragma unroll
        for (int r = 0; r < 2; ++r) {
            const int R = (r == 0) ? R0 : R1;
            const int rowA = R + m;
            const bool anyLow  = (kk*32       <= R + 15);
            const bool lowFull = (kk*32 + 31  <= R);
            const bool anyUp   = (kk*32 + 31  >= R);
            const bool upFull  = (kk*32       >= R + 16);
            s16x8 a = *reinterpret_cast<const s16x8*>(SF + (size_t)rowA*136 + ko);
            if (anyLow) {
                s16x8 aL;
                if (lowFull) aL = a;
                else {
                    #pragma unroll
                    for (int e = 0; e < 8; ++e)
                        aL[e] = (kk*32 + q*8 + e <= rowA) ? a[e] : (short)0;
                }
                #pragma unroll
                for (int ct = 0; ct < 8; ++ct)
                    accA[r][ct] = MFMA16(aL, b[ct], accA[r][ct]);
            }
            if (anyUp) {
                s16x8 aU;
                if (upFull) aU = a;
                else {
                    #pragma unroll
                    for (int e = 0; e < 8; ++e)
                        aU[e] = (kk*32 + q*8 + e >= rowA) ? a[e] : (short)0;
                }
                #pragma unroll
                for (int ct = 0; ct < 8; ++ct)
                    accB[r][ct] = MFMA16(aU, b[ct], accB[r][ct]);
            }
        }
    }

    // ---- phase 3: inter via MFMA; pref -> accA, suf -> accB ----------------
    const u16* pf = prefT + (size_t)(h*NC + c)*SLOT;
    const u16* sf = sufT  + (size_t)(h*NC + c)*SLOT;
    for (int kk = 0; kk < 8; ++kk) {
        const int ko = kk*32 + q*8;
        s16x8 a0 = *reinterpret_cast<const s16x8*>(qbase + (size_t)rowA0*FF + ko);
        s16x8 a1 = *reinterpret_cast<const s16x8*>(qbase + (size_t)rowA1*FF + ko);
        #pragma unroll
        for (int nt = 0; nt < 8; ++nt) {
            s16x8 bp = *reinterpret_cast<const s16x8*>(pf + (size_t)(nt*16 + m)*FF + ko);
            accA[0][nt] = MFMA16(a0, bp, accA[0][nt]);
            accA[1][nt] = MFMA16(a1, bp, accA[1][nt]);
            s16x8 bs = *reinterpret_cast<const s16x8*>(sf + (size_t)(nt*16 + m)*FF + ko);
            accB[0][nt] = MFMA16(a0, bs, accB[0][nt]);
            accB[1][nt] = MFMA16(a1, bs, accB[1][nt]);
        }
    }

    // ---- epilogue: out = accA*ia + accB*ib, direct fragment stores ---------
    #pragma unroll
    for (int r = 0; r < 2; ++r) {
        const int Rb = ((r == 0) ? R0 : R1) + q*4;
        #pragma unroll
        for (int reg = 0; reg < 4; ++reg) {
            const int row = Rb + reg;
            const int pos = c*CHK + row;
            const float ia = 1.0f / (float)(pos + 1);
            const float ib = 1.0f / (float)(SEQ - pos);
            float* orow = out + (tok0 + (size_t)row)*DIM;
            #pragma unroll
            for (int ct = 0; ct < 8; ++ct)
                orow[ct*16 + m] = accA[r][ct][reg]*ia + accB[r][ct][reg]*ib;
        }
    }
}

extern "C" void kernel_launch(void* const* d_in, const int* in_sizes, int n_in,
                              void* d_out, int out_size, void* d_ws, size_t ws_size,
                              hipStream_t stream) {
    const float* q  = (const float*)d_in[0];
    const float* k  = (const float*)d_in[1];
    const float* v  = (const float*)d_in[2];
    const float* w1 = (const float*)d_in[3];
    const float* b1 = (const float*)d_in[4];
    const float* w2 = (const float*)d_in[5];
    const float* b2 = (const float*)d_in[6];
    float* out = (float*)d_out;

    char* ws = (char*)d_ws;
    const size_t phiBytes = (size_t)BH*SEQ*FF*sizeof(u16);   // 50,331,648
    u16* qphi   = (u16*)ws;
    u16* kphi   = (u16*)(ws + phiBytes);
    u16* chunkT = (u16*)(ws + 2*phiBytes);   // becomes prefT in-place after scan
    u16* sufT   = (u16*)(ws + 3*phiBytes);
    u16* w1t    = (u16*)(ws + 4*phiBytes);               // 256*136*2 = 69,632 B
    u16* w2t    = w1t + 256*136;                         // 256*264*2 = 135,168 B
    // total ws = 201,326,592 + 204,800 = 201,531,392 B (< 204,472,320 proven)

    prep_kernel<<<dim3(100), 256, 0, stream>>>(w1, w2, w1t, w2t);
    phi_fused_kernel<<<dim3(2*(BH*SEQ)/PTOK), 512, 0, stream>>>(q, k, b1, b2, w1t, w2t, qphi, kphi);
    kvsum_kernel<<<dim3(NC, BH), 256, 0, stream>>>(kphi, v, chunkT);
    scan_kernel<<<dim3(384), 256, 0, stream>>>(chunkT, sufT);
    out_kernel<<<dim3(NC, BH), 256, 0, stream>>>(qphi, kphi, v, chunkT, sufT, out);
}

// Round 3
// 492.032 us; speedup vs baseline: 3.7847x; 1.4883x over previous
//
#include <hip/hip_runtime.h>

#define BH  24
#define SEQ 4096
#define DIM 128
#define FF  256
#define CHK 128
#define NC  32
#define SLOT (FF*DIM)

typedef unsigned short u16;
typedef unsigned int   u32;
typedef short  s16x8 __attribute__((ext_vector_type(8)));
typedef float  f32x4 __attribute__((ext_vector_type(4)));

#define MFMA16(a,b,c) __builtin_amdgcn_mfma_f32_16x16x32_bf16(a,b,c,0,0,0)

static __device__ __forceinline__ float bf2f(u16 u) {
    return __uint_as_float(((u32)u) << 16);
}
static __device__ __forceinline__ u16 f2bf(float f) {
    u32 u = __float_as_uint(f);
    u += 0x7fffu + ((u >> 16) & 1u);
    return (u16)(u >> 16);
}

// ---------------- weight prep: transposed, padded, bf16 ----------------------
// w1t[f][d]  stride 136  (B-operand for GEMM1: col=f, k=d)
// w2t[e][f]  stride 264  (B-operand for GEMM2: col=e, k=f)
__global__ __launch_bounds__(256) void prep_kernel(
    const float* __restrict__ w1, const float* __restrict__ w2,
    u16* __restrict__ w1t, u16* __restrict__ w2t)
{
    int idx = blockIdx.x * 256 + threadIdx.x;
    int stride = gridDim.x * 256;
    for (int i = idx; i < 256*136; i += stride) {
        int f = i / 136, d = i - f*136;
        w1t[i] = (d < 128) ? f2bf(w1[d*FF + f]) : (u16)0;
    }
    for (int i = idx; i < 256*264; i += stride) {
        int e = i / 264, f = i - e*264;
        w2t[i] = (f < 256) ? f2bf(w2[f*FF + e]) : (u16)0;
    }
}

// ---------------- fused phi via MFMA: y = silu(x@W1+b1)@W2 + b2 --------------
#define PTOK 128
#define XS_OFF   0
#define W1S_OFF  17408
#define HS_OFF   0
#define W2S_OFF  33792
#define YB_OFF   0
#define ARENA_U16 52224   // 104,448 B

__global__ __launch_bounds__(512) void phi_fused_kernel(
    const float* __restrict__ xq, const float* __restrict__ xk,
    const float* __restrict__ b1, const float* __restrict__ b2,
    const u16* __restrict__ w1t, const u16* __restrict__ w2t,
    u16* __restrict__ yq, u16* __restrict__ yk)
{
    __shared__ __align__(16) u16 arena[ARENA_U16];
    const int tid = threadIdx.x;
    int b = blockIdx.x;
    const int nB = (BH*SEQ)/PTOK;   // 768
    const float* xin; u16* yout;
    if (b < nB) { xin = xq; yout = yq; }
    else        { xin = xk; yout = yk; b -= nB; }
    const size_t tok0 = (size_t)b * PTOK;

    const int w = tid >> 6, lane = tid & 63;
    const int m = lane & 15, q = lane >> 4;
    const int wr = w >> 2, wc = w & 3;        // 2 row-groups x 4 col-groups
    const f32x4 zero4 = {0.f, 0.f, 0.f, 0.f};

    // ---- stage XS (fp32 -> bf16) + W1S (linear copy of pre-padded w1t) -----
    {
        const float4* xsrc = reinterpret_cast<const float4*>(xin + tok0*DIM);
        for (int i = tid; i < PTOK*DIM/4; i += 512) {
            int row = i >> 5, c4 = i & 31;
            float4 xv = xsrc[i];
            u32 lo = (u32)f2bf(xv.x) | ((u32)f2bf(xv.y) << 16);
            u32 hi = (u32)f2bf(xv.z) | ((u32)f2bf(xv.w) << 16);
            *reinterpret_cast<uint2*>(arena + XS_OFF + row*136 + c4*4) = make_uint2(lo, hi);
        }
        const uint4* s = reinterpret_cast<const uint4*>(w1t);
        uint4* d = reinterpret_cast<uint4*>(arena + W1S_OFF);
        for (int i = tid; i < (256*136)/8; i += 512) d[i] = s[i];
    }
    __syncthreads();

    // ---- GEMM1: H[128][256] = XS @ W1, K=128 -------------------------------
    f32x4 acc[4][4];
    #pragma unroll
    for (int i = 0; i < 4; ++i)
        #pragma unroll
        for (int ct = 0; ct < 4; ++ct) acc[i][ct] = zero4;

    for (int kk = 0; kk < 4; ++kk) {
        int ko = kk*32 + q*8;
        s16x8 a[4], bb[4];
        #pragma unroll
        for (int i = 0; i < 4; ++i)
            a[i] = *reinterpret_cast<const s16x8*>(arena + XS_OFF + (wr*64 + i*16 + m)*136 + ko);
        #pragma unroll
        for (int ct = 0; ct < 4; ++ct)
            bb[ct] = *reinterpret_cast<const s16x8*>(arena + W1S_OFF + (wc*64 + ct*16 + m)*136 + ko);
        #pragma unroll
        for (int i = 0; i < 4; ++i)
            #pragma unroll
            for (int ct = 0; ct < 4; ++ct)
                acc[i][ct] = MFMA16(a[i], bb[ct], acc[i][ct]);
    }
    __syncthreads();   // all XS/W1S reads done; HS overwrites that space

    // ---- bias + SiLU, write HS bf16 ----------------------------------------
    {
        float b1v[4];
        #pragma unroll
        for (int ct = 0; ct < 4; ++ct) b1v[ct] = b1[wc*64 + ct*16 + m];
        #pragma unroll
        for (int i = 0; i < 4; ++i) {
            #pragma unroll
            for (int ct = 0; ct < 4; ++ct) {
                #pragma unroll
                for (int reg = 0; reg < 4; ++reg) {
                    float h = acc[i][ct][reg] + b1v[ct];
                    h = h / (1.0f + __expf(-h));
                    arena[HS_OFF + (size_t)(wr*64 + i*16 + q*4 + reg)*264 + (wc*64 + ct*16 + m)] = f2bf(h);
                }
            }
        }
    }
    __syncthreads();

    // ---- GEMM2: Y[128][256] = HS @ W2, K=256 in 4 chunks of 64 -------------
    f32x4 acc2[4][4];
    #pragma unroll
    for (int i = 0; i < 4; ++i)
        #pragma unroll
        for (int ct = 0; ct < 4; ++ct) acc2[i][ct] = zero4;

    for (int ch = 0; ch < 4; ++ch) {
        {   // stage W2 chunk [256 e][64 f] -> [256][72]
            const uint4* s = reinterpret_cast<const uint4*>(w2t);
            uint4* d = reinterpret_cast<uint4*>(arena + W2S_OFF);
            for (int i = tid; i < 256*8; i += 512) {
                int e = i >> 3, c = i & 7;
                d[e*9 + c] = s[e*33 + ch*8 + c];
            }
        }
        __syncthreads();
        #pragma unroll
        for (int k2 = 0; k2 < 2; ++k2) {
            int ko = k2*32 + q*8;
            s16x8 a[4], bb[4];
            #pragma unroll
            for (int i = 0; i < 4; ++i)
                a[i] = *reinterpret_cast<const s16x8*>(arena + HS_OFF + (wr*64 + i*16 + m)*264 + ch*64 + ko);
            #pragma unroll
            for (int ct = 0; ct < 4; ++ct)
                bb[ct] = *reinterpret_cast<const s16x8*>(arena + W2S_OFF + (wc*64 + ct*16 + m)*72 + ko);
            #pragma unroll
            for (int i = 0; i < 4; ++i)
                #pragma unroll
                for (int ct = 0; ct < 4; ++ct)
                    acc2[i][ct] = MFMA16(a[i], bb[ct], acc2[i][ct]);
        }
        __syncthreads();
    }

    // ---- bias, Y -> LDS (whole arena dead), coalesced uint4 store ----------
    {
        float b2v[4];
        #pragma unroll
        for (int ct = 0; ct < 4; ++ct) b2v[ct] = b2[wc*64 + ct*16 + m];
        #pragma unroll
        for (int i = 0; i < 4; ++i) {
            #pragma unroll
            for (int ct = 0; ct < 4; ++ct) {
                #pragma unroll
                for (int reg = 0; reg < 4; ++reg) {
                    float y = acc2[i][ct][reg] + b2v[ct];
                    arena[YB_OFF + (size_t)(wr*64 + i*16 + q*4 + reg)*264 + (wc*64 + ct*16 + m)] = f2bf(y);
                }
            }
        }
    }
    __syncthreads();
    {
        uint4* dst = reinterpret_cast<uint4*>(yout + tok0*FF);
        const uint4* srcy = reinterpret_cast<const uint4*>(arena + YB_OFF);
        for (int i = tid; i < PTOK*32; i += 512) {
            int row = i >> 5, c = i & 31;
            dst[i] = srcy[row*33 + c];
        }
    }
}

// ------- per-(head,chunk) KV sums via MFMA -> bf16 TRANSPOSED [d][f] ---------
// chunkT[h][c][d][f] = sum_t kphi[t][f] * v[t][d]
// C[i=f][j=d], A = K^T [f][t], B = V^T [d][t]; t chunked in 2x64.
// LDS: V^T [128][72] + K^T [256][72], strides 9 granules (conflict-free).
#define KVA_OFF 0
#define KVB_OFF (128*72)
#define KV_U16  (128*72 + 256*72)   // 27648 u16 = 55,296 B

__global__ __launch_bounds__(256) void kvsum_kernel(
    const u16* __restrict__ kphi, const float* __restrict__ v,
    u16* __restrict__ chunkT)
{
    __shared__ __align__(16) u16 kv[KV_U16];
    const int c = blockIdx.x, h = blockIdx.y, tid = threadIdx.x;
    const int w = tid >> 6, lane = tid & 63;
    const int m = lane & 15, q = lane >> 4;
    const int wr = w >> 1, wc = w & 1;    // wr: d-half(64), wc: f-half(128)
    const size_t tok0 = (size_t)h*SEQ + (size_t)c*CHK;
    const f32x4 zero4 = {0.f, 0.f, 0.f, 0.f};

    f32x4 acc[8][4];   // [f-tile][d-tile]
    #pragma unroll
    for (int i = 0; i < 8; ++i)
        #pragma unroll
        for (int ct = 0; ct < 4; ++ct) acc[i][ct] = zero4;

    for (int tc = 0; tc < 2; ++tc) {
        // ---- stage K^T: lane<->f (coalesced 128B/wave u16 gathers) ---------
        {
            const u16* kb = kphi + (tok0 + tc*64)*FF + tid;
            #pragma unroll
            for (int tg = 0; tg < 8; ++tg) {
                u16 vals[8];
                #pragma unroll
                for (int tt = 0; tt < 8; ++tt)
                    vals[tt] = kb[(size_t)(tg*8 + tt)*FF];
                uint4 p;
                p.x = (u32)vals[0] | ((u32)vals[1] << 16);
                p.y = (u32)vals[2] | ((u32)vals[3] << 16);
                p.z = (u32)vals[4] | ((u32)vals[5] << 16);
                p.w = (u32)vals[6] | ((u32)vals[7] << 16);
                *reinterpret_cast<uint4*>(kv + KVB_OFF + tid*72 + tg*8) = p;
            }
        }
        // ---- stage V^T: lane<->d (coalesced 256B/wave f32 loads), bf16 -----
        {
            const int d  = tid & 127;
            const int th = tid >> 7;            // t-half of 32
            const float* vb = v + (tok0 + tc*64 + th*32)*DIM + d;
            #pragma unroll
            for (int tg = 0; tg < 4; ++tg) {
                float fv[8];
                #pragma unroll
                for (int tt = 0; tt < 8; ++tt)
                    fv[tt] = vb[(size_t)(tg*8 + tt)*DIM];
                uint4 p;
                p.x = (u32)f2bf(fv[0]) | ((u32)f2bf(fv[1]) << 16);
                p.y = (u32)f2bf(fv[2]) | ((u32)f2bf(fv[3]) << 16);
                p.z = (u32)f2bf(fv[4]) | ((u32)f2bf(fv[5]) << 16);
                p.w = (u32)f2bf(fv[6]) | ((u32)f2bf(fv[7]) << 16);
                *reinterpret_cast<uint4*>(kv + KVA_OFF + d*72 + th*32 + tg*8) = p;
            }
        }
        __syncthreads();

        #pragma unroll
        for (int k2 = 0; k2 < 2; ++k2) {
            const int ko = k2*32 + q*8;
            s16x8 a[8], bb[4];
            #pragma unroll
            for (int i = 0; i < 8; ++i)
                a[i] = *reinterpret_cast<const s16x8*>(kv + KVB_OFF + (wc*128 + i*16 + m)*72 + ko);
            #pragma unroll
            for (int ct = 0; ct < 4; ++ct)
                bb[ct] = *reinterpret_cast<const s16x8*>(kv + KVA_OFF + (wr*64 + ct*16 + m)*72 + ko);
            #pragma unroll
            for (int i = 0; i < 8; ++i)
                #pragma unroll
                for (int ct = 0; ct < 4; ++ct)
                    acc[i][ct] = MFMA16(a[i], bb[ct], acc[i][ct]);
        }
        __syncthreads();   // safe to restage
    }

    // ---- epilogue: C row = f (q*4+reg contiguous!), col = d; uint2 packs ---
    u16* outp = chunkT + (size_t)(h*NC + c)*SLOT;
    #pragma unroll
    for (int i = 0; i < 8; ++i) {
        const int f0 = wc*128 + i*16 + q*4;
        #pragma unroll
        for (int ct = 0; ct < 4; ++ct) {
            const int d = wr*64 + ct*16 + m;
            u32 lo = (u32)f2bf(acc[i][ct][0]) | ((u32)f2bf(acc[i][ct][1]) << 16);
            u32 hi = (u32)f2bf(acc[i][ct][2]) | ((u32)f2bf(acc[i][ct][3]) << 16);
            *reinterpret_cast<uint2*>(outp + (size_t)d*FF + f0) = make_uint2(lo, hi);
        }
    }
}

// ---------------- elementwise scan over chunks (layout-agnostic, proven) -----
__global__ __launch_bounds__(256) void scan_kernel(
    u16* __restrict__ chunkT, u16* __restrict__ sufT)
{
    const int g = blockIdx.x * 256 + threadIdx.x;
    const int h = g >> 12;
    const int e = (g & 4095) * 8;
    u16* base  = chunkT + (size_t)h*NC*SLOT + e;
    u16* sbase = sufT   + (size_t)h*NC*SLOT + e;

    float tot[8];
    #pragma unroll
    for (int i = 0; i < 8; ++i) tot[i] = 0.f;
    for (int c = 0; c < NC; ++c) {
        uint4 r = *reinterpret_cast<const uint4*>(base + (size_t)c*SLOT);
        tot[0] += __uint_as_float(r.x << 16);
        tot[1] += __uint_as_float(r.x & 0xffff0000u);
        tot[2] += __uint_as_float(r.y << 16);
        tot[3] += __uint_as_float(r.y & 0xffff0000u);
        tot[4] += __uint_as_float(r.z << 16);
        tot[5] += __uint_as_float(r.z & 0xffff0000u);
        tot[6] += __uint_as_float(r.w << 16);
        tot[7] += __uint_as_float(r.w & 0xffff0000u);
    }
    float run[8];
    #pragma unroll
    for (int i = 0; i < 8; ++i) run[i] = 0.f;
    for (int c = 0; c < NC; ++c) {
        uint4 r = *reinterpret_cast<const uint4*>(base + (size_t)c*SLOT);
        float old[8];
        old[0] = __uint_as_float(r.x << 16);
        old[1] = __uint_as_float(r.x & 0xffff0000u);
        old[2] = __uint_as_float(r.y << 16);
        old[3] = __uint_as_float(r.y & 0xffff0000u);
        old[4] = __uint_as_float(r.z << 16);
        old[5] = __uint_as_float(r.z & 0xffff0000u);
        old[6] = __uint_as_float(r.w << 16);
        old[7] = __uint_as_float(r.w & 0xffff0000u);
        uint4 wp, wsuf;
        wp.x = (u32)f2bf(run[0]) | ((u32)f2bf(run[1]) << 16);
        wp.y = (u32)f2bf(run[2]) | ((u32)f2bf(run[3]) << 16);
        wp.z = (u32)f2bf(run[4]) | ((u32)f2bf(run[5]) << 16);
        wp.w = (u32)f2bf(run[6]) | ((u32)f2bf(run[7]) << 16);
        *reinterpret_cast<uint4*>(base + (size_t)c*SLOT) = wp;
        #pragma unroll
        for (int i = 0; i < 8; ++i) run[i] += old[i];
        float sf[8];
        #pragma unroll
        for (int i = 0; i < 8; ++i) sf[i] = tot[i] - run[i];
        wsuf.x = (u32)f2bf(sf[0]) | ((u32)f2bf(sf[1]) << 16);
        wsuf.y = (u32)f2bf(sf[2]) | ((u32)f2bf(sf[3]) << 16);
        wsuf.z = (u32)f2bf(sf[4]) | ((u32)f2bf(sf[5]) << 16);
        wsuf.w = (u32)f2bf(sf[6]) | ((u32)f2bf(sf[7]) << 16);
        *reinterpret_cast<uint4*>(sbase + (size_t)c*SLOT) = wsuf;
    }
}

// ------- output: all-MFMA. S->bf16 LDS; masked intra GEMMs; inter GEMMs -----
__global__ __launch_bounds__(256) void out_kernel(
    const u16* __restrict__ qphi, const u16* __restrict__ kphi,
    const float* __restrict__ v,
    const u16* __restrict__ prefT, const u16* __restrict__ sufT,
    float* __restrict__ out)
{
    __shared__ __align__(16) u16 SF[CHK*136];   // S bf16 [i][j], stride 136
    __shared__ __align__(16) u16 VT[DIM*136];   // v^T bf16 [d][j], stride 136
    const int c = blockIdx.x, h = blockIdx.y;
    const int tid = threadIdx.x;
    const int w = tid >> 6, lane = tid & 63;
    const int m = lane & 15, q = lane >> 4;
    const size_t tok0 = (size_t)h*SEQ + (size_t)c*CHK;
    const u16* qbase = qphi + tok0*FF;
    const u16* kbase = kphi + tok0*FF;
    const int R0 = (2*w)*16, R1 = R0 + 16;
    const int rowA0 = R0 + m, rowA1 = R1 + m;
    const f32x4 zero4 = {0.f, 0.f, 0.f, 0.f};

    // ---- stage V^T ----------------------------------------------------------
    {
        const int d  = tid & 127;
        const int j0 = (tid >> 7) * 8;
        const float* vb = v + tok0*DIM + d;
        for (int jb = 0; jb < 8; ++jb) {
            const int jbase = jb*16 + j0;
            float vals[8];
            #pragma unroll
            for (int t = 0; t < 8; ++t) vals[t] = vb[(size_t)(jbase + t)*DIM];
            uint4 p;
            p.x = (u32)f2bf(vals[0]) | ((u32)f2bf(vals[1]) << 16);
            p.y = (u32)f2bf(vals[2]) | ((u32)f2bf(vals[3]) << 16);
            p.z = (u32)f2bf(vals[4]) | ((u32)f2bf(vals[5]) << 16);
            p.w = (u32)f2bf(vals[6]) | ((u32)f2bf(vals[7]) << 16);
            *reinterpret_cast<uint4*>(VT + d*136 + jbase) = p;
        }
    }

    // ---- phase 1: S = Qphi Kphi^T via MFMA, write bf16 SF (own rows only) --
    {
        f32x4 sacc[2][8];
        #pragma unroll
        for (int r = 0; r < 2; ++r)
            #pragma unroll
            for (int ct = 0; ct < 8; ++ct) sacc[r][ct] = zero4;

        for (int kk = 0; kk < 8; ++kk) {
            int ko = kk*32 + q*8;
            s16x8 a0 = *reinterpret_cast<const s16x8*>(qbase + (size_t)rowA0*FF + ko);
            s16x8 a1 = *reinterpret_cast<const s16x8*>(qbase + (size_t)rowA1*FF + ko);
            #pragma unroll
            for (int ct = 0; ct < 8; ++ct) {
                s16x8 b = *reinterpret_cast<const s16x8*>(kbase + (size_t)(ct*16 + m)*FF + ko);
                sacc[0][ct] = MFMA16(a0, b, sacc[0][ct]);
                sacc[1][ct] = MFMA16(a1, b, sacc[1][ct]);
            }
        }
        #pragma unroll
        for (int r = 0; r < 2; ++r) {
            const int R = (r == 0) ? R0 : R1;
            #pragma unroll
            for (int ct = 0; ct < 8; ++ct) {
                #pragma unroll
                for (int reg = 0; reg < 4; ++reg)
                    SF[(size_t)(R + q*4 + reg)*136 + (ct*16 + m)] = f2bf(sacc[r][ct][reg]);
            }
        }
    }
    __syncthreads();

    // ---- phases 2+3 accumulators -------------------------------------------
    f32x4 accA[2][8], accB[2][8];
    #pragma unroll
    for (int r = 0; r < 2; ++r)
        #pragma unroll
        for (int ct = 0; ct < 8; ++ct) { accA[r][ct] = zero4; accB[r][ct] = zero4; }

    // ---- phase 2: intra via triangular-masked MFMA GEMMs -------------------
    #pragma unroll
    for (int kk = 0; kk < 4; ++kk) {
        const int ko = kk*32 + q*8;
        s16x8 b[8];
        #pragma unroll
        for (int ct = 0; ct < 8; ++ct)
            b[ct] = *reinterpret_cast<const s16x8*>(VT + (size_t)(ct*16 + m)*136 + ko);
        #pragma unroll
        for (int r = 0; r < 2; ++r) {
            const int R = (r == 0) ? R0 : R1;
            const int rowA = R + m;
            const bool anyLow  = (kk*32       <= R + 15);
            const bool lowFull = (kk*32 + 31  <= R);
            const bool anyUp   = (kk*32 + 31  >= R);
            const bool upFull  = (kk*32       >= R + 16);
            s16x8 a = *reinterpret_cast<const s16x8*>(SF + (size_t)rowA*136 + ko);
            if (anyLow) {
                s16x8 aL;
                if (lowFull) aL = a;
                else {
                    #pragma unroll
                    for (int e = 0; e < 8; ++e)
                        aL[e] = (kk*32 + q*8 + e <= rowA) ? a[e] : (short)0;
                }
                #pragma unroll
                for (int ct = 0; ct < 8; ++ct)
                    accA[r][ct] = MFMA16(aL, b[ct], accA[r][ct]);
            }
            if (anyUp) {
                s16x8 aU;
                if (upFull) aU = a;
                else {
                    #pragma unroll
                    for (int e = 0; e < 8; ++e)
                        aU[e] = (kk*32 + q*8 + e >= rowA) ? a[e] : (short)0;
                }
                #pragma unroll
                for (int ct = 0; ct < 8; ++ct)
                    accB[r][ct] = MFMA16(aU, b[ct], accB[r][ct]);
            }
        }
    }

    // ---- phase 3: inter via MFMA; pref -> accA, suf -> accB ----------------
    const u16* pf = prefT + (size_t)(h*NC + c)*SLOT;
    const u16* sf = sufT  + (size_t)(h*NC + c)*SLOT;
    for (int kk = 0; kk < 8; ++kk) {
        const int ko = kk*32 + q*8;
        s16x8 a0 = *reinterpret_cast<const s16x8*>(qbase + (size_t)rowA0*FF + ko);
        s16x8 a1 = *reinterpret_cast<const s16x8*>(qbase + (size_t)rowA1*FF + ko);
        #pragma unroll
        for (int nt = 0; nt < 8; ++nt) {
            s16x8 bp = *reinterpret_cast<const s16x8*>(pf + (size_t)(nt*16 + m)*FF + ko);
            accA[0][nt] = MFMA16(a0, bp, accA[0][nt]);
            accA[1][nt] = MFMA16(a1, bp, accA[1][nt]);
            s16x8 bs = *reinterpret_cast<const s16x8*>(sf + (size_t)(nt*16 + m)*FF + ko);
            accB[0][nt] = MFMA16(a0, bs, accB[0][nt]);
            accB[1][nt] = MFMA16(a1, bs, accB[1][nt]);
        }
    }

    // ---- epilogue ----------------------------------------------------------
    #pragma unroll
    for (int r = 0; r < 2; ++r) {
        const int Rb = ((r == 0) ? R0 : R1) + q*4;
        #pragma unroll
        for (int reg = 0; reg < 4; ++reg) {
            const int row = Rb + reg;
            const int pos = c*CHK + row;
            const float ia = 1.0f / (float)(pos + 1);
            const float ib = 1.0f / (float)(SEQ - pos);
            float* orow = out + (tok0 + (size_t)row)*DIM;
            #pragma unroll
            for (int ct = 0; ct < 8; ++ct)
                orow[ct*16 + m] = accA[r][ct][reg]*ia + accB[r][ct][reg]*ib;
        }
    }
}

extern "C" void kernel_launch(void* const* d_in, const int* in_sizes, int n_in,
                              void* d_out, int out_size, void* d_ws, size_t ws_size,
                              hipStream_t stream) {
    const float* q  = (const float*)d_in[0];
    const float* k  = (const float*)d_in[1];
    const float* v  = (const float*)d_in[2];
    const float* w1 = (const float*)d_in[3];
    const float* b1 = (const float*)d_in[4];
    const float* w2 = (const float*)d_in[5];
    const float* b2 = (const float*)d_in[6];
    float* out = (float*)d_out;

    char* ws = (char*)d_ws;
    const size_t phiBytes = (size_t)BH*SEQ*FF*sizeof(u16);   // 50,331,648
    u16* qphi   = (u16*)ws;
    u16* kphi   = (u16*)(ws + phiBytes);
    u16* chunkT = (u16*)(ws + 2*phiBytes);   // becomes prefT in-place after scan
    u16* sufT   = (u16*)(ws + 3*phiBytes);
    u16* w1t    = (u16*)(ws + 4*phiBytes);               // 256*136*2 = 69,632 B
    u16* w2t    = w1t + 256*136;                         // 256*264*2 = 135,168 B

    prep_kernel<<<dim3(100), 256, 0, stream>>>(w1, w2, w1t, w2t);
    phi_fused_kernel<<<dim3(2*(BH*SEQ)/PTOK), 512, 0, stream>>>(q, k, b1, b2, w1t, w2t, qphi, kphi);
    kvsum_kernel<<<dim3(NC, BH), 256, 0, stream>>>(kphi, v, chunkT);
    scan_kernel<<<dim3(384), 256, 0, stream>>>(chunkT, sufT);
    out_kernel<<<dim3(NC, BH), 256, 0, stream>>>(qphi, kphi, v, chunkT, sufT, out);
}

// Round 4
// 481.417 us; speedup vs baseline: 3.8682x; 1.0220x over previous
//
#include <hip/hip_runtime.h>

#define BH  24
#define SEQ 4096
#define DIM 128
#define FF  256
#define CHK 128
#define NC  32
#define SLOT (FF*DIM)

typedef unsigned short u16;
typedef unsigned int   u32;
typedef short  s16x8 __attribute__((ext_vector_type(8)));
typedef float  f32x4 __attribute__((ext_vector_type(4)));

#define MFMA16(a,b,c) __builtin_amdgcn_mfma_f32_16x16x32_bf16(a,b,c,0,0,0)

static __device__ __forceinline__ float bf2f(u16 u) {
    return __uint_as_float(((u32)u) << 16);
}
static __device__ __forceinline__ u16 f2bf(float f) {
    u32 u = __float_as_uint(f);
    u += 0x7fffu + ((u >> 16) & 1u);
    return (u16)(u >> 16);
}

// ---------------- weight prep: transposed, padded, bf16 ----------------------
// w1t[f][d]  stride 136  (B-operand for GEMM1: col=f, k=d)
// w2t[e][f]  stride 264  (B-operand for GEMM2: col=e, k=f)
__global__ __launch_bounds__(256) void prep_kernel(
    const float* __restrict__ w1, const float* __restrict__ w2,
    u16* __restrict__ w1t, u16* __restrict__ w2t)
{
    int idx = blockIdx.x * 256 + threadIdx.x;
    int stride = gridDim.x * 256;
    for (int i = idx; i < 256*136; i += stride) {
        int f = i / 136, d = i - f*136;
        w1t[i] = (d < 128) ? f2bf(w1[d*FF + f]) : (u16)0;
    }
    for (int i = idx; i < 256*264; i += stride) {
        int e = i / 264, f = i - e*264;
        w2t[i] = (f < 256) ? f2bf(w2[f*FF + e]) : (u16)0;
    }
}

// ---------------- fused phi via MFMA: y = silu(x@W1+b1)@W2 + b2 --------------
// 512 threads (8 waves, 2x4 wave grid), 128 tokens/block.
// Weights read as B-fragments DIRECTLY from global (L2-resident, all blocks
// share) -> arena = max(XS 34,816 B; HS/YB 67,584 B) = 67,584 B -> 2 blocks/CU.
#define PTOK 128
#define XS_OFF   0
#define HS_OFF   0
#define YB_OFF   0
#define ARENA_U16 33792   // 67,584 B

__global__ __launch_bounds__(512) void phi_fused_kernel(
    const float* __restrict__ xq, const float* __restrict__ xk,
    const float* __restrict__ b1, const float* __restrict__ b2,
    const u16* __restrict__ w1t, const u16* __restrict__ w2t,
    u16* __restrict__ yq, u16* __restrict__ yk)
{
    __shared__ __align__(16) u16 arena[ARENA_U16];
    const int tid = threadIdx.x;
    int b = blockIdx.x;
    const int nB = (BH*SEQ)/PTOK;   // 768
    const float* xin; u16* yout;
    if (b < nB) { xin = xq; yout = yq; }
    else        { xin = xk; yout = yk; b -= nB; }
    const size_t tok0 = (size_t)b * PTOK;

    const int w = tid >> 6, lane = tid & 63;
    const int m = lane & 15, q = lane >> 4;
    const int wr = w >> 2, wc = w & 3;        // 2 row-groups x 4 col-groups
    const f32x4 zero4 = {0.f, 0.f, 0.f, 0.f};

    // ---- stage XS (fp32 -> bf16) -------------------------------------------
    {
        const float4* xsrc = reinterpret_cast<const float4*>(xin + tok0*DIM);
        for (int i = tid; i < PTOK*DIM/4; i += 512) {
            int row = i >> 5, c4 = i & 31;
            float4 xv = xsrc[i];
            u32 lo = (u32)f2bf(xv.x) | ((u32)f2bf(xv.y) << 16);
            u32 hi = (u32)f2bf(xv.z) | ((u32)f2bf(xv.w) << 16);
            *reinterpret_cast<uint2*>(arena + XS_OFF + row*136 + c4*4) = make_uint2(lo, hi);
        }
    }
    __syncthreads();   // sync1: XS visible

    // ---- GEMM1: H[128][256] = XS @ W1 (B-frags from global w1t), K=128 -----
    f32x4 acc[4][4];
    #pragma unroll
    for (int i = 0; i < 4; ++i)
        #pragma unroll
        for (int ct = 0; ct < 4; ++ct) acc[i][ct] = zero4;

    #pragma unroll
    for (int kk = 0; kk < 4; ++kk) {
        int ko = kk*32 + q*8;
        s16x8 a[4], bb[4];
        #pragma unroll
        for (int ct = 0; ct < 4; ++ct)
            bb[ct] = *reinterpret_cast<const s16x8*>(w1t + (size_t)(wc*64 + ct*16 + m)*136 + ko);
        #pragma unroll
        for (int i = 0; i < 4; ++i)
            a[i] = *reinterpret_cast<const s16x8*>(arena + XS_OFF + (wr*64 + i*16 + m)*136 + ko);
        #pragma unroll
        for (int i = 0; i < 4; ++i)
            #pragma unroll
            for (int ct = 0; ct < 4; ++ct)
                acc[i][ct] = MFMA16(a[i], bb[ct], acc[i][ct]);
    }
    __syncthreads();   // sync2: XS reads done; HS overwrites that space

    // ---- bias + SiLU, write HS bf16 ----------------------------------------
    {
        float b1v[4];
        #pragma unroll
        for (int ct = 0; ct < 4; ++ct) b1v[ct] = b1[wc*64 + ct*16 + m];
        #pragma unroll
        for (int i = 0; i < 4; ++i) {
            #pragma unroll
            for (int ct = 0; ct < 4; ++ct) {
                #pragma unroll
                for (int reg = 0; reg < 4; ++reg) {
                    float h = acc[i][ct][reg] + b1v[ct];
                    h = h / (1.0f + __expf(-h));
                    arena[HS_OFF + (size_t)(wr*64 + i*16 + q*4 + reg)*264 + (wc*64 + ct*16 + m)] = f2bf(h);
                }
            }
        }
    }
    __syncthreads();   // sync3: HS visible

    // ---- GEMM2: Y[128][256] = HS @ W2 (B-frags from global w2t), K=256 -----
    f32x4 acc2[4][4];
    #pragma unroll
    for (int i = 0; i < 4; ++i)
        #pragma unroll
        for (int ct = 0; ct < 4; ++ct) acc2[i][ct] = zero4;

    #pragma unroll
    for (int kk = 0; kk < 8; ++kk) {
        int ko = kk*32 + q*8;
        s16x8 a[4], bb[4];
        #pragma unroll
        for (int ct = 0; ct < 4; ++ct)
            bb[ct] = *reinterpret_cast<const s16x8*>(w2t + (size_t)(wc*64 + ct*16 + m)*264 + ko);
        #pragma unroll
        for (int i = 0; i < 4; ++i)
            a[i] = *reinterpret_cast<const s16x8*>(arena + HS_OFF + (wr*64 + i*16 + m)*264 + ko);
        #pragma unroll
        for (int i = 0; i < 4; ++i)
            #pragma unroll
            for (int ct = 0; ct < 4; ++ct)
                acc2[i][ct] = MFMA16(a[i], bb[ct], acc2[i][ct]);
    }
    __syncthreads();   // sync4: HS reads done; YB overwrites

    // ---- bias, Y -> LDS, coalesced uint4 store -----------------------------
    {
        float b2v[4];
        #pragma unroll
        for (int ct = 0; ct < 4; ++ct) b2v[ct] = b2[wc*64 + ct*16 + m];
        #pragma unroll
        for (int i = 0; i < 4; ++i) {
            #pragma unroll
            for (int ct = 0; ct < 4; ++ct) {
                #pragma unroll
                for (int reg = 0; reg < 4; ++reg) {
                    float y = acc2[i][ct][reg] + b2v[ct];
                    arena[YB_OFF + (size_t)(wr*64 + i*16 + q*4 + reg)*264 + (wc*64 + ct*16 + m)] = f2bf(y);
                }
            }
        }
    }
    __syncthreads();   // sync5: YB visible
    {
        uint4* dst = reinterpret_cast<uint4*>(yout + tok0*FF);
        const uint4* srcy = reinterpret_cast<const uint4*>(arena + YB_OFF);
        for (int i = tid; i < PTOK*32; i += 512) {
            int row = i >> 5, c = i & 31;
            dst[i] = srcy[row*33 + c];
        }
    }
}

// ------- per-(head,chunk) KV sums via MFMA -> bf16 TRANSPOSED [d][f] ---------
#define KVA_OFF 0
#define KVB_OFF (128*72)
#define KV_U16  (128*72 + 256*72)   // 27648 u16 = 55,296 B

__global__ __launch_bounds__(256) void kvsum_kernel(
    const u16* __restrict__ kphi, const float* __restrict__ v,
    u16* __restrict__ chunkT)
{
    __shared__ __align__(16) u16 kv[KV_U16];
    const int c = blockIdx.x, h = blockIdx.y, tid = threadIdx.x;
    const int w = tid >> 6, lane = tid & 63;
    const int m = lane & 15, q = lane >> 4;
    const int wr = w >> 1, wc = w & 1;    // wr: d-half(64), wc: f-half(128)
    const size_t tok0 = (size_t)h*SEQ + (size_t)c*CHK;
    const f32x4 zero4 = {0.f, 0.f, 0.f, 0.f};

    f32x4 acc[8][4];   // [f-tile][d-tile]
    #pragma unroll
    for (int i = 0; i < 8; ++i)
        #pragma unroll
        for (int ct = 0; ct < 4; ++ct) acc[i][ct] = zero4;

    for (int tc = 0; tc < 2; ++tc) {
        // ---- stage K^T: lane<->f (coalesced 128B/wave u16 gathers) ---------
        {
            const u16* kb = kphi + (tok0 + tc*64)*FF + tid;
            #pragma unroll
            for (int tg = 0; tg < 8; ++tg) {
                u16 vals[8];
                #pragma unroll
                for (int tt = 0; tt < 8; ++tt)
                    vals[tt] = kb[(size_t)(tg*8 + tt)*FF];
                uint4 p;
                p.x = (u32)vals[0] | ((u32)vals[1] << 16);
                p.y = (u32)vals[2] | ((u32)vals[3] << 16);
                p.z = (u32)vals[4] | ((u32)vals[5] << 16);
                p.w = (u32)vals[6] | ((u32)vals[7] << 16);
                *reinterpret_cast<uint4*>(kv + KVB_OFF + tid*72 + tg*8) = p;
            }
        }
        // ---- stage V^T: lane<->d (coalesced 256B/wave f32 loads), bf16 -----
        {
            const int d  = tid & 127;
            const int th = tid >> 7;            // t-half of 32
            const float* vb = v + (tok0 + tc*64 + th*32)*DIM + d;
            #pragma unroll
            for (int tg = 0; tg < 4; ++tg) {
                float fv[8];
                #pragma unroll
                for (int tt = 0; tt < 8; ++tt)
                    fv[tt] = vb[(size_t)(tg*8 + tt)*DIM];
                uint4 p;
                p.x = (u32)f2bf(fv[0]) | ((u32)f2bf(fv[1]) << 16);
                p.y = (u32)f2bf(fv[2]) | ((u32)f2bf(fv[3]) << 16);
                p.z = (u32)f2bf(fv[4]) | ((u32)f2bf(fv[5]) << 16);
                p.w = (u32)f2bf(fv[6]) | ((u32)f2bf(fv[7]) << 16);
                *reinterpret_cast<uint4*>(kv + KVA_OFF + d*72 + th*32 + tg*8) = p;
            }
        }
        __syncthreads();

        #pragma unroll
        for (int k2 = 0; k2 < 2; ++k2) {
            const int ko = k2*32 + q*8;
            s16x8 a[8], bb[4];
            #pragma unroll
            for (int i = 0; i < 8; ++i)
                a[i] = *reinterpret_cast<const s16x8*>(kv + KVB_OFF + (wc*128 + i*16 + m)*72 + ko);
            #pragma unroll
            for (int ct = 0; ct < 4; ++ct)
                bb[ct] = *reinterpret_cast<const s16x8*>(kv + KVA_OFF + (wr*64 + ct*16 + m)*72 + ko);
            #pragma unroll
            for (int i = 0; i < 8; ++i)
                #pragma unroll
                for (int ct = 0; ct < 4; ++ct)
                    acc[i][ct] = MFMA16(a[i], bb[ct], acc[i][ct]);
        }
        __syncthreads();   // safe to restage
    }

    // ---- epilogue: C row = f (q*4+reg contiguous!), col = d; uint2 packs ---
    u16* outp = chunkT + (size_t)(h*NC + c)*SLOT;
    #pragma unroll
    for (int i = 0; i < 8; ++i) {
        const int f0 = wc*128 + i*16 + q*4;
        #pragma unroll
        for (int ct = 0; ct < 4; ++ct) {
            const int d = wr*64 + ct*16 + m;
            u32 lo = (u32)f2bf(acc[i][ct][0]) | ((u32)f2bf(acc[i][ct][1]) << 16);
            u32 hi = (u32)f2bf(acc[i][ct][2]) | ((u32)f2bf(acc[i][ct][3]) << 16);
            *reinterpret_cast<uint2*>(outp + (size_t)d*FF + f0) = make_uint2(lo, hi);
        }
    }
}

// ---------------- elementwise scan over chunks (layout-agnostic, proven) -----
__global__ __launch_bounds__(256) void scan_kernel(
    u16* __restrict__ chunkT, u16* __restrict__ sufT)
{
    const int g = blockIdx.x * 256 + threadIdx.x;
    const int h = g >> 12;
    const int e = (g & 4095) * 8;
    u16* base  = chunkT + (size_t)h*NC*SLOT + e;
    u16* sbase = sufT   + (size_t)h*NC*SLOT + e;

    float tot[8];
    #pragma unroll
    for (int i = 0; i < 8; ++i) tot[i] = 0.f;
    for (int c = 0; c < NC; ++c) {
        uint4 r = *reinterpret_cast<const uint4*>(base + (size_t)c*SLOT);
        tot[0] += __uint_as_float(r.x << 16);
        tot[1] += __uint_as_float(r.x & 0xffff0000u);
        tot[2] += __uint_as_float(r.y << 16);
        tot[3] += __uint_as_float(r.y & 0xffff0000u);
        tot[4] += __uint_as_float(r.z << 16);
        tot[5] += __uint_as_float(r.z & 0xffff0000u);
        tot[6] += __uint_as_float(r.w << 16);
        tot[7] += __uint_as_float(r.w & 0xffff0000u);
    }
    float run[8];
    #pragma unroll
    for (int i = 0; i < 8; ++i) run[i] = 0.f;
    for (int c = 0; c < NC; ++c) {
        uint4 r = *reinterpret_cast<const uint4*>(base + (size_t)c*SLOT);
        float old[8];
        old[0] = __uint_as_float(r.x << 16);
        old[1] = __uint_as_float(r.x & 0xffff0000u);
        old[2] = __uint_as_float(r.y << 16);
        old[3] = __uint_as_float(r.y & 0xffff0000u);
        old[4] = __uint_as_float(r.z << 16);
        old[5] = __uint_as_float(r.z & 0xffff0000u);
        old[6] = __uint_as_float(r.w << 16);
        old[7] = __uint_as_float(r.w & 0xffff0000u);
        uint4 wp, wsuf;
        wp.x = (u32)f2bf(run[0]) | ((u32)f2bf(run[1]) << 16);
        wp.y = (u32)f2bf(run[2]) | ((u32)f2bf(run[3]) << 16);
        wp.z = (u32)f2bf(run[4]) | ((u32)f2bf(run[5]) << 16);
        wp.w = (u32)f2bf(run[6]) | ((u32)f2bf(run[7]) << 16);
        *reinterpret_cast<uint4*>(base + (size_t)c*SLOT) = wp;
        #pragma unroll
        for (int i = 0; i < 8; ++i) run[i] += old[i];
        float sf[8];
        #pragma unroll
        for (int i = 0; i < 8; ++i) sf[i] = tot[i] - run[i];
        wsuf.x = (u32)f2bf(sf[0]) | ((u32)f2bf(sf[1]) << 16);
        wsuf.y = (u32)f2bf(sf[2]) | ((u32)f2bf(sf[3]) << 16);
        wsuf.z = (u32)f2bf(sf[4]) | ((u32)f2bf(sf[5]) << 16);
        wsuf.w = (u32)f2bf(sf[6]) | ((u32)f2bf(sf[7]) << 16);
        *reinterpret_cast<uint4*>(sbase + (size_t)c*SLOT) = wsuf;
    }
}

// ------- output: all-MFMA. S->bf16 LDS; masked intra GEMMs; inter GEMMs -----
__global__ __launch_bounds__(256) void out_kernel(
    const u16* __restrict__ qphi, const u16* __restrict__ kphi,
    const float* __restrict__ v,
    const u16* __restrict__ prefT, const u16* __restrict__ sufT,
    float* __restrict__ out)
{
    __shared__ __align__(16) u16 SF[CHK*136];   // S bf16 [i][j], stride 136
    __shared__ __align__(16) u16 VT[DIM*136];   // v^T bf16 [d][j], stride 136
    const int c = blockIdx.x, h = blockIdx.y;
    const int tid = threadIdx.x;
    const int w = tid >> 6, lane = tid & 63;
    const int m = lane & 15, q = lane >> 4;
    const size_t tok0 = (size_t)h*SEQ + (size_t)c*CHK;
    const u16* qbase = qphi + tok0*FF;
    const u16* kbase = kphi + tok0*FF;
    const int R0 = (2*w)*16, R1 = R0 + 16;
    const int rowA0 = R0 + m, rowA1 = R1 + m;
    const f32x4 zero4 = {0.f, 0.f, 0.f, 0.f};

    // ---- stage V^T ----------------------------------------------------------
    {
        const int d  = tid & 127;
        const int j0 = (tid >> 7) * 8;
        const float* vb = v + tok0*DIM + d;
        for (int jb = 0; jb < 8; ++jb) {
            const int jbase = jb*16 + j0;
            float vals[8];
            #pragma unroll
            for (int t = 0; t < 8; ++t) vals[t] = vb[(size_t)(jbase + t)*DIM];
            uint4 p;
            p.x = (u32)f2bf(vals[0]) | ((u32)f2bf(vals[1]) << 16);
            p.y = (u32)f2bf(vals[2]) | ((u32)f2bf(vals[3]) << 16);
            p.z = (u32)f2bf(vals[4]) | ((u32)f2bf(vals[5]) << 16);
            p.w = (u32)f2bf(vals[6]) | ((u32)f2bf(vals[7]) << 16);
            *reinterpret_cast<uint4*>(VT + d*136 + jbase) = p;
        }
    }

    // ---- phase 1: S = Qphi Kphi^T via MFMA, write bf16 SF (own rows only) --
    {
        f32x4 sacc[2][8];
        #pragma unroll
        for (int r = 0; r < 2; ++r)
            #pragma unroll
            for (int ct = 0; ct < 8; ++ct) sacc[r][ct] = zero4;

        for (int kk = 0; kk < 8; ++kk) {
            int ko = kk*32 + q*8;
            s16x8 a0 = *reinterpret_cast<const s16x8*>(qbase + (size_t)rowA0*FF + ko);
            s16x8 a1 = *reinterpret_cast<const s16x8*>(qbase + (size_t)rowA1*FF + ko);
            #pragma unroll
            for (int ct = 0; ct < 8; ++ct) {
                s16x8 b = *reinterpret_cast<const s16x8*>(kbase + (size_t)(ct*16 + m)*FF + ko);
                sacc[0][ct] = MFMA16(a0, b, sacc[0][ct]);
                sacc[1][ct] = MFMA16(a1, b, sacc[1][ct]);
            }
        }
        #pragma unroll
        for (int r = 0; r < 2; ++r) {
            const int R = (r == 0) ? R0 : R1;
            #pragma unroll
            for (int ct = 0; ct < 8; ++ct) {
                #pragma unroll
                for (int reg = 0; reg < 4; ++reg)
                    SF[(size_t)(R + q*4 + reg)*136 + (ct*16 + m)] = f2bf(sacc[r][ct][reg]);
            }
        }
    }
    __syncthreads();

    // ---- phases 2+3 accumulators -------------------------------------------
    f32x4 accA[2][8], accB[2][8];
    #pragma unroll
    for (int r = 0; r < 2; ++r)
        #pragma unroll
        for (int ct = 0; ct < 8; ++ct) { accA[r][ct] = zero4; accB[r][ct] = zero4; }

    // ---- phase 2: intra via triangular-masked MFMA GEMMs -------------------
    #pragma unroll
    for (int kk = 0; kk < 4; ++kk) {
        const int ko = kk*32 + q*8;
        s16x8 b[8];
        #pragma unroll
        for (int ct = 0; ct < 8; ++ct)
            b[ct] = *reinterpret_cast<const s16x8*>(VT + (size_t)(ct*16 + m)*136 + ko);
        #pragma unroll
        for (int r = 0; r < 2; ++r) {
            const int R = (r == 0) ? R0 : R1;
            const int rowA = R + m;
            const bool anyLow  = (kk*32       <= R + 15);
            const bool lowFull = (kk*32 + 31  <= R);
            const bool anyUp   = (kk*32 + 31  >= R);
            const bool upFull  = (kk*32       >= R + 16);
            s16x8 a = *reinterpret_cast<const s16x8*>(SF + (size_t)rowA*136 + ko);
            if (anyLow) {
                s16x8 aL;
                if (lowFull) aL = a;
                else {
                    #pragma unroll
                    for (int e = 0; e < 8; ++e)
                        aL[e] = (kk*32 + q*8 + e <= rowA) ? a[e] : (short)0;
                }
                #pragma unroll
                for (int ct = 0; ct < 8; ++ct)
                    accA[r][ct] = MFMA16(aL, b[ct], accA[r][ct]);
            }
            if (anyUp) {
                s16x8 aU;
                if (upFull) aU = a;
                else {
                    #pragma unroll
                    for (int e = 0; e < 8; ++e)
                        aU[e] = (kk*32 + q*8 + e >= rowA) ? a[e] : (short)0;
                }
                #pragma unroll
                for (int ct = 0; ct < 8; ++ct)
                    accB[r][ct] = MFMA16(aU, b[ct], accB[r][ct]);
            }
        }
    }

    // ---- phase 3: inter via MFMA; pref -> accA, suf -> accB ----------------
    const u16* pf = prefT + (size_t)(h*NC + c)*SLOT;
    const u16* sf = sufT  + (size_t)(h*NC + c)*SLOT;
    for (int kk = 0; kk < 8; ++kk) {
        const int ko = kk*32 + q*8;
        s16x8 a0 = *reinterpret_cast<const s16x8*>(qbase + (size_t)rowA0*FF + ko);
        s16x8 a1 = *reinterpret_cast<const s16x8*>(qbase + (size_t)rowA1*FF + ko);
        #pragma unroll
        for (int nt = 0; nt < 8; ++nt) {
            s16x8 bp = *reinterpret_cast<const s16x8*>(pf + (size_t)(nt*16 + m)*FF + ko);
            accA[0][nt] = MFMA16(a0, bp, accA[0][nt]);
            accA[1][nt] = MFMA16(a1, bp, accA[1][nt]);
            s16x8 bs = *reinterpret_cast<const s16x8*>(sf + (size_t)(nt*16 + m)*FF + ko);
            accB[0][nt] = MFMA16(a0, bs, accB[0][nt]);
            accB[1][nt] = MFMA16(a1, bs, accB[1][nt]);
        }
    }

    // ---- epilogue ----------------------------------------------------------
    #pragma unroll
    for (int r = 0; r < 2; ++r) {
        const int Rb = ((r == 0) ? R0 : R1) + q*4;
        #pragma unroll
        for (int reg = 0; reg < 4; ++reg) {
            const int row = Rb + reg;
            const int pos = c*CHK + row;
            const float ia = 1.0f / (float)(pos + 1);
            const float ib = 1.0f / (float)(SEQ - pos);
            float* orow = out + (tok0 + (size_t)row)*DIM;
            #pragma unroll
            for (int ct = 0; ct < 8; ++ct)
                orow[ct*16 + m] = accA[r][ct][reg]*ia + accB[r][ct][reg]*ib;
        }
    }
}

extern "C" void kernel_launch(void* const* d_in, const int* in_sizes, int n_in,
                              void* d_out, int out_size, void* d_ws, size_t ws_size,
                              hipStream_t stream) {
    const float* q  = (const float*)d_in[0];
    const float* k  = (const float*)d_in[1];
    const float* v  = (const float*)d_in[2];
    const float* w1 = (const float*)d_in[3];
    const float* b1 = (const float*)d_in[4];
    const float* w2 = (const float*)d_in[5];
    const float* b2 = (const float*)d_in[6];
    float* out = (float*)d_out;

    char* ws = (char*)d_ws;
    const size_t phiBytes = (size_t)BH*SEQ*FF*sizeof(u16);   // 50,331,648
    u16* qphi   = (u16*)ws;
    u16* kphi   = (u16*)(ws + phiBytes);
    u16* chunkT = (u16*)(ws + 2*phiBytes);   // becomes prefT in-place after scan
    u16* sufT   = (u16*)(ws + 3*phiBytes);
    u16* w1t    = (u16*)(ws + 4*phiBytes);               // 256*136*2 = 69,632 B
    u16* w2t    = w1t + 256*136;                         // 256*264*2 = 135,168 B

    prep_kernel<<<dim3(100), 256, 0, stream>>>(w1, w2, w1t, w2t);
    phi_fused_kernel<<<dim3(2*(BH*SEQ)/PTOK), 512, 0, stream>>>(q, k, b1, b2, w1t, w2t, qphi, kphi);
    kvsum_kernel<<<dim3(NC, BH), 256, 0, stream>>>(kphi, v, chunkT);
    scan_kernel<<<dim3(384), 256, 0, stream>>>(chunkT, sufT);
    out_kernel<<<dim3(NC, BH), 256, 0, stream>>>(qphi, kphi, v, chunkT, sufT, out);
}

// Round 5
// 469.148 us; speedup vs baseline: 3.9693x; 1.0262x over previous
//
#include <hip/hip_runtime.h>

#define BH  24
#define SEQ 4096
#define DIM 128
#define FF  256
#define CHK 128
#define NC  32
#define SLOT (FF*DIM)

typedef unsigned short u16;
typedef unsigned int   u32;
typedef short  s16x8 __attribute__((ext_vector_type(8)));
typedef float  f32x4 __attribute__((ext_vector_type(4)));

#define MFMA16(a,b,c) __builtin_amdgcn_mfma_f32_16x16x32_bf16(a,b,c,0,0,0)

static __device__ __forceinline__ float bf2f(u16 u) {
    return __uint_as_float(((u32)u) << 16);
}
static __device__ __forceinline__ u16 f2bf(float f) {
    u32 u = __float_as_uint(f);
    u += 0x7fffu + ((u >> 16) & 1u);
    return (u16)(u >> 16);
}

// ---------------- weight prep: transposed, padded, bf16 ----------------------
// w1t[f][d]  stride 136  (B-operand for GEMM1: col=f, k=d)
// w2t[e][f]  stride 264  (B-operand for GEMM2: col=e, k=f)
__global__ __launch_bounds__(256) void prep_kernel(
    const float* __restrict__ w1, const float* __restrict__ w2,
    u16* __restrict__ w1t, u16* __restrict__ w2t)
{
    int idx = blockIdx.x * 256 + threadIdx.x;
    int stride = gridDim.x * 256;
    for (int i = idx; i < 256*136; i += stride) {
        int f = i / 136, d = i - f*136;
        w1t[i] = (d < 128) ? f2bf(w1[d*FF + f]) : (u16)0;
    }
    for (int i = idx; i < 256*264; i += stride) {
        int e = i / 264, f = i - e*264;
        w2t[i] = (f < 256) ? f2bf(w2[f*FF + e]) : (u16)0;
    }
}

// ---------------- fused phi via MFMA: y = silu(x@W1+b1)@W2 + b2 --------------
// 512 threads (8 waves, 2x4 wave grid), 64 tokens/block (PTOK=64 -> arena
// 33,792 B -> 3-4 blocks/CU resident, vs 2 at PTOK=128; latency-hiding fix).
// Weights read as B-fragments DIRECTLY from global (L2-resident, shared).
#define PTOK 64
#define XS_OFF   0
#define HS_OFF   0
#define YB_OFF   0
#define ARENA_U16 16896   // 33,792 B  (HS 64x264; XS 64x136 overlaps)

__global__ __launch_bounds__(512) void phi_fused_kernel(
    const float* __restrict__ xq, const float* __restrict__ xk,
    const float* __restrict__ b1, const float* __restrict__ b2,
    const u16* __restrict__ w1t, const u16* __restrict__ w2t,
    u16* __restrict__ yq, u16* __restrict__ yk)
{
    __shared__ __align__(16) u16 arena[ARENA_U16];
    const int tid = threadIdx.x;
    int b = blockIdx.x;
    const int nB = (BH*SEQ)/PTOK;   // 1536
    const float* xin; u16* yout;
    if (b < nB) { xin = xq; yout = yq; }
    else        { xin = xk; yout = yk; b -= nB; }
    const size_t tok0 = (size_t)b * PTOK;

    const int w = tid >> 6, lane = tid & 63;
    const int m = lane & 15, q = lane >> 4;
    const int wr = w >> 2, wc = w & 3;        // 2 row-groups(32) x 4 col-groups(64)
    const f32x4 zero4 = {0.f, 0.f, 0.f, 0.f};

    // ---- stage XS (fp32 -> bf16), [64][136] --------------------------------
    {
        const float4* xsrc = reinterpret_cast<const float4*>(xin + tok0*DIM);
        for (int i = tid; i < PTOK*DIM/4; i += 512) {
            int row = i >> 5, c4 = i & 31;
            float4 xv = xsrc[i];
            u32 lo = (u32)f2bf(xv.x) | ((u32)f2bf(xv.y) << 16);
            u32 hi = (u32)f2bf(xv.z) | ((u32)f2bf(xv.w) << 16);
            *reinterpret_cast<uint2*>(arena + XS_OFF + row*136 + c4*4) = make_uint2(lo, hi);
        }
    }
    __syncthreads();   // sync1: XS visible

    // ---- GEMM1: H[64][256] = XS @ W1 (B-frags from global w1t), K=128 ------
    f32x4 acc[2][4];
    #pragma unroll
    for (int i = 0; i < 2; ++i)
        #pragma unroll
        for (int ct = 0; ct < 4; ++ct) acc[i][ct] = zero4;

    #pragma unroll
    for (int kk = 0; kk < 4; ++kk) {
        int ko = kk*32 + q*8;
        s16x8 a[2], bb[4];
        #pragma unroll
        for (int ct = 0; ct < 4; ++ct)
            bb[ct] = *reinterpret_cast<const s16x8*>(w1t + (size_t)(wc*64 + ct*16 + m)*136 + ko);
        #pragma unroll
        for (int i = 0; i < 2; ++i)
            a[i] = *reinterpret_cast<const s16x8*>(arena + XS_OFF + (wr*32 + i*16 + m)*136 + ko);
        #pragma unroll
        for (int i = 0; i < 2; ++i)
            #pragma unroll
            for (int ct = 0; ct < 4; ++ct)
                acc[i][ct] = MFMA16(a[i], bb[ct], acc[i][ct]);
    }
    __syncthreads();   // sync2: XS reads done; HS overwrites that space

    // ---- bias + SiLU, write HS bf16 [64][264] ------------------------------
    {
        float b1v[4];
        #pragma unroll
        for (int ct = 0; ct < 4; ++ct) b1v[ct] = b1[wc*64 + ct*16 + m];
        #pragma unroll
        for (int i = 0; i < 2; ++i) {
            #pragma unroll
            for (int ct = 0; ct < 4; ++ct) {
                #pragma unroll
                for (int reg = 0; reg < 4; ++reg) {
                    float h = acc[i][ct][reg] + b1v[ct];
                    h = h / (1.0f + __expf(-h));
                    arena[HS_OFF + (size_t)(wr*32 + i*16 + q*4 + reg)*264 + (wc*64 + ct*16 + m)] = f2bf(h);
                }
            }
        }
    }
    __syncthreads();   // sync3: HS visible

    // ---- GEMM2: Y[64][256] = HS @ W2 (B-frags from global w2t), K=256 ------
    f32x4 acc2[2][4];
    #pragma unroll
    for (int i = 0; i < 2; ++i)
        #pragma unroll
        for (int ct = 0; ct < 4; ++ct) acc2[i][ct] = zero4;

    #pragma unroll
    for (int kk = 0; kk < 8; ++kk) {
        int ko = kk*32 + q*8;
        s16x8 a[2], bb[4];
        #pragma unroll
        for (int ct = 0; ct < 4; ++ct)
            bb[ct] = *reinterpret_cast<const s16x8*>(w2t + (size_t)(wc*64 + ct*16 + m)*264 + ko);
        #pragma unroll
        for (int i = 0; i < 2; ++i)
            a[i] = *reinterpret_cast<const s16x8*>(arena + HS_OFF + (wr*32 + i*16 + m)*264 + ko);
        #pragma unroll
        for (int i = 0; i < 2; ++i)
            #pragma unroll
            for (int ct = 0; ct < 4; ++ct)
                acc2[i][ct] = MFMA16(a[i], bb[ct], acc2[i][ct]);
    }
    __syncthreads();   // sync4: HS reads done; YB overwrites

    // ---- bias, Y -> LDS, coalesced uint4 store -----------------------------
    {
        float b2v[4];
        #pragma unroll
        for (int ct = 0; ct < 4; ++ct) b2v[ct] = b2[wc*64 + ct*16 + m];
        #pragma unroll
        for (int i = 0; i < 2; ++i) {
            #pragma unroll
            for (int ct = 0; ct < 4; ++ct) {
                #pragma unroll
                for (int reg = 0; reg < 4; ++reg) {
                    float y = acc2[i][ct][reg] + b2v[ct];
                    arena[YB_OFF + (size_t)(wr*32 + i*16 + q*4 + reg)*264 + (wc*64 + ct*16 + m)] = f2bf(y);
                }
            }
        }
    }
    __syncthreads();   // sync5: YB visible
    {
        uint4* dst = reinterpret_cast<uint4*>(yout + tok0*FF);
        const uint4* srcy = reinterpret_cast<const uint4*>(arena + YB_OFF);
        for (int i = tid; i < PTOK*32; i += 512) {
            int row = i >> 5, c = i & 31;
            dst[i] = srcy[row*33 + c];
        }
    }
}

// ------- per-(head,chunk) KV sums via MFMA -> bf16 TRANSPOSED [d][f] ---------
#define KVA_OFF 0
#define KVB_OFF (128*72)
#define KV_U16  (128*72 + 256*72)   // 27648 u16 = 55,296 B

__global__ __launch_bounds__(256) void kvsum_kernel(
    const u16* __restrict__ kphi, const float* __restrict__ v,
    u16* __restrict__ chunkT)
{
    __shared__ __align__(16) u16 kv[KV_U16];
    const int c = blockIdx.x, h = blockIdx.y, tid = threadIdx.x;
    const int w = tid >> 6, lane = tid & 63;
    const int m = lane & 15, q = lane >> 4;
    const int wr = w >> 1, wc = w & 1;    // wr: d-half(64), wc: f-half(128)
    const size_t tok0 = (size_t)h*SEQ + (size_t)c*CHK;
    const f32x4 zero4 = {0.f, 0.f, 0.f, 0.f};

    f32x4 acc[8][4];   // [f-tile][d-tile]
    #pragma unroll
    for (int i = 0; i < 8; ++i)
        #pragma unroll
        for (int ct = 0; ct < 4; ++ct) acc[i][ct] = zero4;

    for (int tc = 0; tc < 2; ++tc) {
        // ---- stage K^T: lane<->f (coalesced 128B/wave u16 gathers) ---------
        {
            const u16* kb = kphi + (tok0 + tc*64)*FF + tid;
            #pragma unroll
            for (int tg = 0; tg < 8; ++tg) {
                u16 vals[8];
                #pragma unroll
                for (int tt = 0; tt < 8; ++tt)
                    vals[tt] = kb[(size_t)(tg*8 + tt)*FF];
                uint4 p;
                p.x = (u32)vals[0] | ((u32)vals[1] << 16);
                p.y = (u32)vals[2] | ((u32)vals[3] << 16);
                p.z = (u32)vals[4] | ((u32)vals[5] << 16);
                p.w = (u32)vals[6] | ((u32)vals[7] << 16);
                *reinterpret_cast<uint4*>(kv + KVB_OFF + tid*72 + tg*8) = p;
            }
        }
        // ---- stage V^T: lane<->d (coalesced 256B/wave f32 loads), bf16 -----
        {
            const int d  = tid & 127;
            const int th = tid >> 7;            // t-half of 32
            const float* vb = v + (tok0 + tc*64 + th*32)*DIM + d;
            #pragma unroll
            for (int tg = 0; tg < 4; ++tg) {
                float fv[8];
                #pragma unroll
                for (int tt = 0; tt < 8; ++tt)
                    fv[tt] = vb[(size_t)(tg*8 + tt)*DIM];
                uint4 p;
                p.x = (u32)f2bf(fv[0]) | ((u32)f2bf(fv[1]) << 16);
                p.y = (u32)f2bf(fv[2]) | ((u32)f2bf(fv[3]) << 16);
                p.z = (u32)f2bf(fv[4]) | ((u32)f2bf(fv[5]) << 16);
                p.w = (u32)f2bf(fv[6]) | ((u32)f2bf(fv[7]) << 16);
                *reinterpret_cast<uint4*>(kv + KVA_OFF + d*72 + th*32 + tg*8) = p;
            }
        }
        __syncthreads();

        #pragma unroll
        for (int k2 = 0; k2 < 2; ++k2) {
            const int ko = k2*32 + q*8;
            s16x8 a[8], bb[4];
            #pragma unroll
            for (int i = 0; i < 8; ++i)
                a[i] = *reinterpret_cast<const s16x8*>(kv + KVB_OFF + (wc*128 + i*16 + m)*72 + ko);
            #pragma unroll
            for (int ct = 0; ct < 4; ++ct)
                bb[ct] = *reinterpret_cast<const s16x8*>(kv + KVA_OFF + (wr*64 + ct*16 + m)*72 + ko);
            #pragma unroll
            for (int i = 0; i < 8; ++i)
                #pragma unroll
                for (int ct = 0; ct < 4; ++ct)
                    acc[i][ct] = MFMA16(a[i], bb[ct], acc[i][ct]);
        }
        __syncthreads();   // safe to restage
    }

    // ---- epilogue: C row = f (q*4+reg contiguous!), col = d; uint2 packs ---
    u16* outp = chunkT + (size_t)(h*NC + c)*SLOT;
    #pragma unroll
    for (int i = 0; i < 8; ++i) {
        const int f0 = wc*128 + i*16 + q*4;
        #pragma unroll
        for (int ct = 0; ct < 4; ++ct) {
            const int d = wr*64 + ct*16 + m;
            u32 lo = (u32)f2bf(acc[i][ct][0]) | ((u32)f2bf(acc[i][ct][1]) << 16);
            u32 hi = (u32)f2bf(acc[i][ct][2]) | ((u32)f2bf(acc[i][ct][3]) << 16);
            *reinterpret_cast<uint2*>(outp + (size_t)d*FF + f0) = make_uint2(lo, hi);
        }
    }
}

// ---------------- elementwise scan over chunks (layout-agnostic, proven) -----
__global__ __launch_bounds__(256) void scan_kernel(
    u16* __restrict__ chunkT, u16* __restrict__ sufT)
{
    const int g = blockIdx.x * 256 + threadIdx.x;
    const int h = g >> 12;
    const int e = (g & 4095) * 8;
    u16* base  = chunkT + (size_t)h*NC*SLOT + e;
    u16* sbase = sufT   + (size_t)h*NC*SLOT + e;

    float tot[8];
    #pragma unroll
    for (int i = 0; i < 8; ++i) tot[i] = 0.f;
    for (int c = 0; c < NC; ++c) {
        uint4 r = *reinterpret_cast<const uint4*>(base + (size_t)c*SLOT);
        tot[0] += __uint_as_float(r.x << 16);
        tot[1] += __uint_as_float(r.x & 0xffff0000u);
        tot[2] += __uint_as_float(r.y << 16);
        tot[3] += __uint_as_float(r.y & 0xffff0000u);
        tot[4] += __uint_as_float(r.z << 16);
        tot[5] += __uint_as_float(r.z & 0xffff0000u);
        tot[6] += __uint_as_float(r.w << 16);
        tot[7] += __uint_as_float(r.w & 0xffff0000u);
    }
    float run[8];
    #pragma unroll
    for (int i = 0; i < 8; ++i) run[i] = 0.f;
    for (int c = 0; c < NC; ++c) {
        uint4 r = *reinterpret_cast<const uint4*>(base + (size_t)c*SLOT);
        float old[8];
        old[0] = __uint_as_float(r.x << 16);
        old[1] = __uint_as_float(r.x & 0xffff0000u);
        old[2] = __uint_as_float(r.y << 16);
        old[3] = __uint_as_float(r.y & 0xffff0000u);
        old[4] = __uint_as_float(r.z << 16);
        old[5] = __uint_as_float(r.z & 0xffff0000u);
        old[6] = __uint_as_float(r.w << 16);
        old[7] = __uint_as_float(r.w & 0xffff0000u);
        uint4 wp, wsuf;
        wp.x = (u32)f2bf(run[0]) | ((u32)f2bf(run[1]) << 16);
        wp.y = (u32)f2bf(run[2]) | ((u32)f2bf(run[3]) << 16);
        wp.z = (u32)f2bf(run[4]) | ((u32)f2bf(run[5]) << 16);
        wp.w = (u32)f2bf(run[6]) | ((u32)f2bf(run[7]) << 16);
        *reinterpret_cast<uint4*>(base + (size_t)c*SLOT) = wp;
        #pragma unroll
        for (int i = 0; i < 8; ++i) run[i] += old[i];
        float sf[8];
        #pragma unroll
        for (int i = 0; i < 8; ++i) sf[i] = tot[i] - run[i];
        wsuf.x = (u32)f2bf(sf[0]) | ((u32)f2bf(sf[1]) << 16);
        wsuf.y = (u32)f2bf(sf[2]) | ((u32)f2bf(sf[3]) << 16);
        wsuf.z = (u32)f2bf(sf[4]) | ((u32)f2bf(sf[5]) << 16);
        wsuf.w = (u32)f2bf(sf[6]) | ((u32)f2bf(sf[7]) << 16);
        *reinterpret_cast<uint4*>(sbase + (size_t)c*SLOT) = wsuf;
    }
}

// ------- output: all-MFMA. S->bf16 LDS; masked intra GEMMs; inter GEMMs -----
__global__ __launch_bounds__(256) void out_kernel(
    const u16* __restrict__ qphi, const u16* __restrict__ kphi,
    const float* __restrict__ v,
    const u16* __restrict__ prefT, const u16* __restrict__ sufT,
    float* __restrict__ out)
{
    __shared__ __align__(16) u16 SF[CHK*136];   // S bf16 [i][j], stride 136
    __shared__ __align__(16) u16 VT[DIM*136];   // v^T bf16 [d][j], stride 136
    const int c = blockIdx.x, h = blockIdx.y;
    const int tid = threadIdx.x;
    const int w = tid >> 6, lane = tid & 63;
    const int m = lane & 15, q = lane >> 4;
    const size_t tok0 = (size_t)h*SEQ + (size_t)c*CHK;
    const u16* qbase = qphi + tok0*FF;
    const u16* kbase = kphi + tok0*FF;
    const int R0 = (2*w)*16, R1 = R0 + 16;
    const int rowA0 = R0 + m, rowA1 = R1 + m;
    const f32x4 zero4 = {0.f, 0.f, 0.f, 0.f};

    // ---- stage V^T ----------------------------------------------------------
    {
        const int d  = tid & 127;
        const int j0 = (tid >> 7) * 8;
        const float* vb = v + tok0*DIM + d;
        for (int jb = 0; jb < 8; ++jb) {
            const int jbase = jb*16 + j0;
            float vals[8];
            #pragma unroll
            for (int t = 0; t < 8; ++t) vals[t] = vb[(size_t)(jbase + t)*DIM];
            uint4 p;
            p.x = (u32)f2bf(vals[0]) | ((u32)f2bf(vals[1]) << 16);
            p.y = (u32)f2bf(vals[2]) | ((u32)f2bf(vals[3]) << 16);
            p.z = (u32)f2bf(vals[4]) | ((u32)f2bf(vals[5]) << 16);
            p.w = (u32)f2bf(vals[6]) | ((u32)f2bf(vals[7]) << 16);
            *reinterpret_cast<uint4*>(VT + d*136 + jbase) = p;
        }
    }

    // ---- phase 1: S = Qphi Kphi^T via MFMA, write bf16 SF (own rows only) --
    {
        f32x4 sacc[2][8];
        #pragma unroll
        for (int r = 0; r < 2; ++r)
            #pragma unroll
            for (int ct = 0; ct < 8; ++ct) sacc[r][ct] = zero4;

        for (int kk = 0; kk < 8; ++kk) {
            int ko = kk*32 + q*8;
            s16x8 a0 = *reinterpret_cast<const s16x8*>(qbase + (size_t)rowA0*FF + ko);
            s16x8 a1 = *reinterpret_cast<const s16x8*>(qbase + (size_t)rowA1*FF + ko);
            #pragma unroll
            for (int ct = 0; ct < 8; ++ct) {
                s16x8 b = *reinterpret_cast<const s16x8*>(kbase + (size_t)(ct*16 + m)*FF + ko);
                sacc[0][ct] = MFMA16(a0, b, sacc[0][ct]);
                sacc[1][ct] = MFMA16(a1, b, sacc[1][ct]);
            }
        }
        #pragma unroll
        for (int r = 0; r < 2; ++r) {
            const int R = (r == 0) ? R0 : R1;
            #pragma unroll
            for (int ct = 0; ct < 8; ++ct) {
                #pragma unroll
                for (int reg = 0; reg < 4; ++reg)
                    SF[(size_t)(R + q*4 + reg)*136 + (ct*16 + m)] = f2bf(sacc[r][ct][reg]);
            }
        }
    }
    __syncthreads();

    // ---- phases 2+3 accumulators -------------------------------------------
    f32x4 accA[2][8], accB[2][8];
    #pragma unroll
    for (int r = 0; r < 2; ++r)
        #pragma unroll
        for (int ct = 0; ct < 8; ++ct) { accA[r][ct] = zero4; accB[r][ct] = zero4; }

    // ---- phase 2: intra via triangular-masked MFMA GEMMs -------------------
    #pragma unroll
    for (int kk = 0; kk < 4; ++kk) {
        const int ko = kk*32 + q*8;
        s16x8 b[8];
        #pragma unroll
        for (int ct = 0; ct < 8; ++ct)
            b[ct] = *reinterpret_cast<const s16x8*>(VT + (size_t)(ct*16 + m)*136 + ko);
        #pragma unroll
        for (int r = 0; r < 2; ++r) {
            const int R = (r == 0) ? R0 : R1;
            const int rowA = R + m;
            const bool anyLow  = (kk*32       <= R + 15);
            const bool lowFull = (kk*32 + 31  <= R);
            const bool anyUp   = (kk*32 + 31  >= R);
            const bool upFull  = (kk*32       >= R + 16);
            s16x8 a = *reinterpret_cast<const s16x8*>(SF + (size_t)rowA*136 + ko);
            if (anyLow) {
                s16x8 aL;
                if (lowFull) aL = a;
                else {
                    #pragma unroll
                    for (int e = 0; e < 8; ++e)
                        aL[e] = (kk*32 + q*8 + e <= rowA) ? a[e] : (short)0;
                }
                #pragma unroll
                for (int ct = 0; ct < 8; ++ct)
                    accA[r][ct] = MFMA16(aL, b[ct], accA[r][ct]);
            }
            if (anyUp) {
                s16x8 aU;
                if (upFull) aU = a;
                else {
                    #pragma unroll
                    for (int e = 0; e < 8; ++e)
                        aU[e] = (kk*32 + q*8 + e >= rowA) ? a[e] : (short)0;
                }
                #pragma unroll
                for (int ct = 0; ct < 8; ++ct)
                    accB[r][ct] = MFMA16(aU, b[ct], accB[r][ct]);
            }
        }
    }

    // ---- phase 3: inter via MFMA; pref -> accA, suf -> accB ----------------
    const u16* pf = prefT + (size_t)(h*NC + c)*SLOT;
    const u16* sf = sufT  + (size_t)(h*NC + c)*SLOT;
    for (int kk = 0; kk < 8; ++kk) {
        const int ko = kk*32 + q*8;
        s16x8 a0 = *reinterpret_cast<const s16x8*>(qbase + (size_t)rowA0*FF + ko);
        s16x8 a1 = *reinterpret_cast<const s16x8*>(qbase + (size_t)rowA1*FF + ko);
        #pragma unroll
        for (int nt = 0; nt < 8; ++nt) {
            s16x8 bp = *reinterpret_cast<const s16x8*>(pf + (size_t)(nt*16 + m)*FF + ko);
            accA[0][nt] = MFMA16(a0, bp, accA[0][nt]);
            accA[1][nt] = MFMA16(a1, bp, accA[1][nt]);
            s16x8 bs = *reinterpret_cast<const s16x8*>(sf + (size_t)(nt*16 + m)*FF + ko);
            accB[0][nt] = MFMA16(a0, bs, accB[0][nt]);
            accB[1][nt] = MFMA16(a1, bs, accB[1][nt]);
        }
    }

    // ---- epilogue ----------------------------------------------------------
    #pragma unroll
    for (int r = 0; r < 2; ++r) {
        const int Rb = ((r == 0) ? R0 : R1) + q*4;
        #pragma unroll
        for (int reg = 0; reg < 4; ++reg) {
            const int row = Rb + reg;
            const int pos = c*CHK + row;
            const float ia = 1.0f / (float)(pos + 1);
            const float ib = 1.0f / (float)(SEQ - pos);
            float* orow = out + (tok0 + (size_t)row)*DIM;
            #pragma unroll
            for (int ct = 0; ct < 8; ++ct)
                orow[ct*16 + m] = accA[r][ct][reg]*ia + accB[r][ct][reg]*ib;
        }
    }
}

extern "C" void kernel_launch(void* const* d_in, const int* in_sizes, int n_in,
                              void* d_out, int out_size, void* d_ws, size_t ws_size,
                              hipStream_t stream) {
    const float* q  = (const float*)d_in[0];
    const float* k  = (const float*)d_in[1];
    const float* v  = (const float*)d_in[2];
    const float* w1 = (const float*)d_in[3];
    const float* b1 = (const float*)d_in[4];
    const float* w2 = (const float*)d_in[5];
    const float* b2 = (const float*)d_in[6];
    float* out = (float*)d_out;

    char* ws = (char*)d_ws;
    const size_t phiBytes = (size_t)BH*SEQ*FF*sizeof(u16);   // 50,331,648
    u16* qphi   = (u16*)ws;
    u16* kphi   = (u16*)(ws + phiBytes);
    u16* chunkT = (u16*)(ws + 2*phiBytes);   // becomes prefT in-place after scan
    u16* sufT   = (u16*)(ws + 3*phiBytes);
    u16* w1t    = (u16*)(ws + 4*phiBytes);               // 256*136*2 = 69,632 B
    u16* w2t    = w1t + 256*136;                         // 256*264*2 = 135,168 B

    prep_kernel<<<dim3(100), 256, 0, stream>>>(w1, w2, w1t, w2t);
    phi_fused_kernel<<<dim3(2*(BH*SEQ)/PTOK), 512, 0, stream>>>(q, k, b1, b2, w1t, w2t, qphi, kphi);
    kvsum_kernel<<<dim3(NC, BH), 256, 0, stream>>>(kphi, v, chunkT);
    scan_kernel<<<dim3(384), 256, 0, stream>>>(chunkT, sufT);
    out_kernel<<<dim3(NC, BH), 256, 0, stream>>>(qphi, kphi, v, chunkT, sufT, out);
}